// Round 3
// baseline (975.361 us; speedup 1.0000x reference)
//
#include <hip/hip_runtime.h>
#include <hip/hip_fp16.h>

#define C 128
#define QC 32    // channels per quarter (4 quarters x 2 XCDs)
#define NBUCK 256
#define NSLICE 8

typedef float f4_t __attribute__((ext_vector_type(4)));
typedef unsigned int u4_t __attribute__((ext_vector_type(4)));

// ---------------------------------------------------------------------------
__global__ void zero_cnt_kernel(int* __restrict__ cnt, int n) {
    int i = blockIdx.x * blockDim.x + threadIdx.x;
    if (i < n) cnt[i] = 0;
}

// sliced count: block b handles dst-slice b&7 only -> XCD-local atomics
__global__ void count_kernel(const int* __restrict__ dst, int* __restrict__ cnt,
                             int E, int nps) {
    int slice = blockIdx.x & 7;
    int chunk = blockIdx.x >> 3;
    int nchunks = gridDim.x >> 3;
    int per = (E + nchunks - 1) / nchunks;
    int beg = chunk * per;
    int end = beg + per; if (end > E) end = E;
    int lo = slice * nps, hi = lo + nps;
    for (int e = beg + threadIdx.x; e < end; e += blockDim.x) {
        int d = dst[e];
        if (d >= lo && d < hi) atomicAdd(&cnt[d], 1);
    }
}

// ---- 3-phase parallel exclusive scan of cnt[0..n) --------------------------
__global__ void scan_reduce_kernel(const int* __restrict__ cnt, int* __restrict__ psum, int n) {
    __shared__ int s[256];
    int t = threadIdx.x;
    int i = blockIdx.x * 256 + t;
    s[t] = (i < n) ? cnt[i] : 0;
    __syncthreads();
    for (int off = 128; off > 0; off >>= 1) {
        if (t < off) s[t] += s[t + off];
        __syncthreads();
    }
    if (t == 0) psum[blockIdx.x] = s[0];
}

__global__ void scan_partials_kernel(const int* __restrict__ psum, int* __restrict__ bpre,
                                     int* __restrict__ offsets, int n, int nb) {
    __shared__ int s[256];
    int t = threadIdx.x;
    s[t] = (t < nb) ? psum[t] : 0;
    __syncthreads();
    for (int off = 1; off < 256; off <<= 1) {
        int v = 0;
        if (t >= off) v = s[t - off];
        __syncthreads();
        if (t >= off) s[t] += v;
        __syncthreads();
    }
    bpre[t] = (t == 0) ? 0 : s[t - 1];
    if (t == 255) offsets[n] = s[255];
}

__global__ void scan_apply_kernel(const int* __restrict__ cnt, const int* __restrict__ bpre,
                                  int* __restrict__ offsets, int* __restrict__ cursor,
                                  float* __restrict__ dinv, int n) {
    __shared__ int s[256];
    int t = threadIdx.x;
    int i = blockIdx.x * 256 + t;
    int c = (i < n) ? cnt[i] : 0;
    s[t] = c;
    __syncthreads();
    for (int off = 1; off < 256; off <<= 1) {
        int v = 0;
        if (t >= off) v = s[t - off];
        __syncthreads();
        if (t >= off) s[t] += v;
        __syncthreads();
    }
    if (i < n) {
        int excl = bpre[blockIdx.x] + s[t] - c;
        offsets[i] = excl;
        cursor[i]  = excl;
        dinv[i]    = rsqrtf((float)(c + 1));
    }
}

// ---- degree bucket sort -> perm (ascending degree) -------------------------
__global__ void hist_zero_kernel(int* __restrict__ hist) { hist[threadIdx.x] = 0; }

__global__ void hist_kernel(const int* __restrict__ cnt, int* __restrict__ hist, int n) {
    __shared__ int lh[NBUCK];
    int t = threadIdx.x;
    lh[t] = 0;
    __syncthreads();
    for (int i = blockIdx.x * blockDim.x + t; i < n; i += gridDim.x * blockDim.x) {
        int d = cnt[i]; if (d > NBUCK - 1) d = NBUCK - 1;
        atomicAdd(&lh[d], 1);
    }
    __syncthreads();
    int c = lh[t];
    if (c) atomicAdd(&hist[t], c);
}

__global__ void hist_scan_kernel(const int* __restrict__ hist, int* __restrict__ bcur) {
    __shared__ int s[256];
    int t = threadIdx.x;
    s[t] = hist[t];
    __syncthreads();
    for (int off = 1; off < 256; off <<= 1) {
        int v = 0;
        if (t >= off) v = s[t - off];
        __syncthreads();
        if (t >= off) s[t] += v;
        __syncthreads();
    }
    bcur[t] = (t == 0) ? 0 : s[t - 1];
}

__global__ void perm_kernel(const int* __restrict__ cnt, int* __restrict__ bcur,
                            int* __restrict__ perm, int n) {
    __shared__ int lhist[NBUCK];
    __shared__ int lbase[NBUCK];
    int t = threadIdx.x;
    lhist[t] = 0;
    __syncthreads();
    int i = blockIdx.x * 256 + t;
    int d = 0, lr = 0;
    if (i < n) {
        d = cnt[i]; if (d > NBUCK - 1) d = NBUCK - 1;
        lr = atomicAdd(&lhist[d], 1);
    }
    __syncthreads();
    int c = lhist[t];
    if (c > 0) lbase[t] = atomicAdd(&bcur[t], c);
    __syncthreads();
    if (i < n) perm[lbase[d] + lr] = i;
}

// ---- sliced counting-sort scatter: XCD-local CSR writes --------------------
__global__ void scatter_kernel(const int* __restrict__ src, const int* __restrict__ dst,
                               int* __restrict__ cursor, int* __restrict__ sorted_src,
                               int E, int nps) {
    int slice = blockIdx.x & 7;
    int chunk = blockIdx.x >> 3;
    int nchunks = gridDim.x >> 3;
    int per = (E + nchunks - 1) / nchunks;
    int beg = chunk * per;
    int end = beg + per; if (end > E) end = E;
    int lo = slice * nps, hi = lo + nps;
    for (int e = beg + threadIdx.x; e < end; e += blockDim.x) {
        int d = dst[e];
        if (d >= lo && d < hi) {
            int pos = atomicAdd(&cursor[d], 1);
            sorted_src[pos] = src[e];
        }
    }
}

// int -> u16 index compaction (N < 65536): halves the per-step index stream
__global__ void cvt_u16_kernel(const int* __restrict__ in, unsigned short* __restrict__ out,
                               int E) {
    int i = blockIdx.x * blockDim.x + threadIdx.x;
    int b = i * 4;
    if (b + 3 < E) {
        int4 v = ((const int4*)in)[i];
        ushort4 o;
        o.x = (unsigned short)v.x; o.y = (unsigned short)v.y;
        o.z = (unsigned short)v.z; o.w = (unsigned short)v.w;
        ((ushort4*)out)[i] = o;
    } else if (b < E) {
        for (int q = b; q < E; ++q) out[q] = (unsigned short)in[q];
    }
}

// y0: quarter layout [quarter][N][32ch] fp16 = dinv*x.
// hidden (nullable): if non-null, also write coeffs[0]*x (fallback RMW scheme).
__global__ void init_kernel(const float* __restrict__ x, const float* __restrict__ coeffs,
                            const float* __restrict__ dinv, float* __restrict__ hidden,
                            uint4* __restrict__ y0, int N) {
    int i = blockIdx.x * blockDim.x + threadIdx.x;   // over N*16 groups of 8 ch
    if (i >= N * 16) return;
    int node = i >> 4;
    int g = i & 15;            // 8-channel group within the 128-ch row
    int qt = g >> 2;           // quarter
    int jj = g & 3;            // uint4 slot within 64-B quarter row
    float dv = dinv[node];
    const float4* xp = (const float4*)(x + (size_t)node * C + g * 8);
    float4 x0 = xp[0], x1 = xp[1];
    if (hidden) {
        float g0 = coeffs[0];
        float4* hp = (float4*)(hidden + (size_t)node * C + g * 8);
        hp[0] = make_float4(g0 * x0.x, g0 * x0.y, g0 * x0.z, g0 * x0.w);
        hp[1] = make_float4(g0 * x1.x, g0 * x1.y, g0 * x1.z, g0 * x1.w);
    }
    __half2 p0 = __floats2half2_rn(dv * x0.x, dv * x0.y);
    __half2 p1 = __floats2half2_rn(dv * x0.z, dv * x0.w);
    __half2 p2 = __floats2half2_rn(dv * x1.x, dv * x1.y);
    __half2 p3 = __floats2half2_rn(dv * x1.z, dv * x1.w);
    uint4 u;
    u.x = *reinterpret_cast<unsigned int*>(&p0);
    u.y = *reinterpret_cast<unsigned int*>(&p1);
    u.z = *reinterpret_cast<unsigned int*>(&p2);
    u.w = *reinterpret_cast<unsigned int*>(&p3);
    y0[(size_t)qt * N * 4 + (size_t)node * 4 + jj] = u;
}

// ---------------------------------------------------------------------------
__device__ __forceinline__ void acc8(float* a, uint4 u) {
    __half2* h = (__half2*)&u;
    #pragma unroll
    for (int i = 0; i < 4; ++i) {
        float2 f = __half22float2(h[i]);
        a[2 * i]     += f.x;
        a[2 * i + 1] += f.y;
    }
}

// quarter-sliced propagation step. Channel quarters (32 ch = 3.2 MB buffer)
// partitioned across XCD pairs: XCDs {2q,2q+1} gather only quarter q's input
// buffer -> fully L2-resident (3.2 MB < 4 MB). Output stores + index streams
// are nontemporal so they don't evict the resident input.
// block = 256 thr = 4 waves = 64 nodes (4 lanes/node, lane owns 16 B of a
// 64-B quarter row). hidden nullable: null => deferred accumulation scheme.
template<typename IdxT>
__global__ __launch_bounds__(256)
void prop4_kernel(const uint4* __restrict__ yin, uint4* __restrict__ yout,
                  float* __restrict__ hidden, const float* __restrict__ coeffs, int k,
                  const int* __restrict__ offsets, const IdxT* __restrict__ srcs,
                  const float* __restrict__ dinv, const int* __restrict__ perm, int n) {
    int bid = blockIdx.x;
    int qt  = (bid & 7) >> 1;              // XCD pair -> quarter (perf-only map)
    int qb  = (bid >> 3) * 2 + (bid & 1);  // block index within the quarter
    int t = threadIdx.x;
    int lane = t & 63;
    int grp  = lane >> 2;          // node within wave: 0..15
    int j    = lane & 3;           // 16-B slice within 64-B quarter row
    int slot = qb * 64 + (t >> 6) * 16 + grp;
    if (slot >= n) return;
    int v   = __builtin_nontemporal_load(perm + slot);
    int beg = __builtin_nontemporal_load(offsets + v);
    int end = __builtin_nontemporal_load(offsets + v + 1);
    float dv = __builtin_nontemporal_load(dinv + v);
    float gamma = coeffs[k];

    size_t qs = (size_t)n * 4;             // uint4 per quarter buffer
    const uint4* base = yin + (size_t)qt * qs;
    float A0[8] = {0,0,0,0,0,0,0,0};
    float A1[8] = {0,0,0,0,0,0,0,0};
    float A2[8] = {0,0,0,0,0,0,0,0};
    float A3[8] = {0,0,0,0,0,0,0,0};

    int e = beg;
    for (; e + 8 <= end; e += 8) {
        int s0 = (int)__builtin_nontemporal_load(srcs + e);
        int s1 = (int)__builtin_nontemporal_load(srcs + e + 1);
        int s2 = (int)__builtin_nontemporal_load(srcs + e + 2);
        int s3 = (int)__builtin_nontemporal_load(srcs + e + 3);
        int s4 = (int)__builtin_nontemporal_load(srcs + e + 4);
        int s5 = (int)__builtin_nontemporal_load(srcs + e + 5);
        int s6 = (int)__builtin_nontemporal_load(srcs + e + 6);
        int s7 = (int)__builtin_nontemporal_load(srcs + e + 7);
        uint4 u0 = base[(size_t)s0 * 4 + j];
        uint4 u1 = base[(size_t)s1 * 4 + j];
        uint4 u2 = base[(size_t)s2 * 4 + j];
        uint4 u3 = base[(size_t)s3 * 4 + j];
        uint4 u4 = base[(size_t)s4 * 4 + j];
        uint4 u5 = base[(size_t)s5 * 4 + j];
        uint4 u6 = base[(size_t)s6 * 4 + j];
        uint4 u7 = base[(size_t)s7 * 4 + j];
        acc8(A0, u0); acc8(A1, u1); acc8(A2, u2); acc8(A3, u3);
        acc8(A0, u4); acc8(A1, u5); acc8(A2, u6); acc8(A3, u7);
    }
    for (; e + 4 <= end; e += 4) {
        int s0 = (int)__builtin_nontemporal_load(srcs + e);
        int s1 = (int)__builtin_nontemporal_load(srcs + e + 1);
        int s2 = (int)__builtin_nontemporal_load(srcs + e + 2);
        int s3 = (int)__builtin_nontemporal_load(srcs + e + 3);
        uint4 u0 = base[(size_t)s0 * 4 + j];
        uint4 u1 = base[(size_t)s1 * 4 + j];
        uint4 u2 = base[(size_t)s2 * 4 + j];
        uint4 u3 = base[(size_t)s3 * 4 + j];
        acc8(A0, u0); acc8(A1, u1); acc8(A2, u2); acc8(A3, u3);
    }
    for (; e < end; ++e) {
        int s0 = (int)__builtin_nontemporal_load(srcs + e);
        uint4 u = base[(size_t)s0 * 4 + j];
        acc8(A0, u);
    }
    // self-loop term
    uint4 us = base[(size_t)v * 4 + j];
    acc8(A1, us);

    float xn[8];
    #pragma unroll
    for (int i = 0; i < 8; ++i)
        xn[i] = dv * ((A0[i] + A1[i]) + (A2[i] + A3[i]));

    if (hidden) {
        // fallback scheme: per-step RMW (nontemporal to protect y residency)
        f4_t* hp = (f4_t*)(hidden + (size_t)v * C + qt * QC + j * 8);
        f4_t h0 = __builtin_nontemporal_load(hp);
        f4_t h1 = __builtin_nontemporal_load(hp + 1);
        h0.x += gamma * xn[0]; h0.y += gamma * xn[1]; h0.z += gamma * xn[2]; h0.w += gamma * xn[3];
        h1.x += gamma * xn[4]; h1.y += gamma * xn[5]; h1.z += gamma * xn[6]; h1.w += gamma * xn[7];
        __builtin_nontemporal_store(h0, hp);
        __builtin_nontemporal_store(h1, hp + 1);
    }

    // yout = half(dinv * xn) -- nontemporal: do not evict the input slab
    __half2 p0 = __floats2half2_rn(dv * xn[0], dv * xn[1]);
    __half2 p1 = __floats2half2_rn(dv * xn[2], dv * xn[3]);
    __half2 p2 = __floats2half2_rn(dv * xn[4], dv * xn[5]);
    __half2 p3 = __floats2half2_rn(dv * xn[6], dv * xn[7]);
    u4_t u;
    u.x = *reinterpret_cast<unsigned int*>(&p0);
    u.y = *reinterpret_cast<unsigned int*>(&p1);
    u.z = *reinterpret_cast<unsigned int*>(&p2);
    u.w = *reinterpret_cast<unsigned int*>(&p3);
    u4_t* outp = (u4_t*)(yout + (size_t)qt * qs + (size_t)v * 4 + j);
    __builtin_nontemporal_store(u, outp);
}

// deferred hidden build: hidden = coeffs[0]*x + sum_k coeffs[k] * y_k / dinv.
// one thread per 8 channels; all reads fully coalesced.
__global__ void final_kernel(const float* __restrict__ x, const float* __restrict__ coeffs,
                             const float* __restrict__ dinv, const uint4* __restrict__ Y4,
                             float* __restrict__ hidden, int N, int K) {
    int i = blockIdx.x * blockDim.x + threadIdx.x;
    if (i >= N * 16) return;
    int node = i >> 4;
    int g = i & 15;
    int qt = g >> 2;
    int jj = g & 3;
    float g0 = coeffs[0];
    float rdv = 1.0f / dinv[node];           // = sqrt(deg+1)
    const float4* xp = (const float4*)(x + (size_t)node * C + g * 8);
    float4 x0 = xp[0], x1 = xp[1];
    float a[8] = {g0 * x0.x, g0 * x0.y, g0 * x0.z, g0 * x0.w,
                  g0 * x1.x, g0 * x1.y, g0 * x1.z, g0 * x1.w};
    size_t qs = (size_t)N * 4;               // uint4 per quarter buffer
    size_t row = (size_t)qt * qs + (size_t)node * 4 + jj;
    size_t slab = (size_t)N * 16;            // uint4 per k-slab (all 4 quarters)
    for (int k = 1; k <= K; ++k) {
        float s = coeffs[k] * rdv;
        uint4 u = Y4[(size_t)k * slab + row];
        __half2* h = (__half2*)&u;
        #pragma unroll
        for (int q2 = 0; q2 < 4; ++q2) {
            float2 f = __half22float2(h[q2]);
            a[2 * q2]     += s * f.x;
            a[2 * q2 + 1] += s * f.y;
        }
    }
    float4* hp = (float4*)(hidden + (size_t)node * C + g * 8);
    hp[0] = make_float4(a[0], a[1], a[2], a[3]);
    hp[1] = make_float4(a[4], a[5], a[6], a[7]);
}

extern "C" void kernel_launch(void* const* d_in, const int* in_sizes, int n_in,
                              void* d_out, int out_size, void* d_ws, size_t ws_size,
                              hipStream_t stream) {
    const float* x      = (const float*)d_in[0];
    const float* coeffs = (const float*)d_in[1];
    const int*   edge   = (const int*)d_in[2];

    const int N = in_sizes[0] / C;          // 50000
    const int K = in_sizes[1] - 1;          // 10
    const int E = in_sizes[2] / 2;          // 1,600,000
    const int* src = edge;
    const int* dst = edge + E;

    char* ws = (char*)d_ws;
    auto alloc = [&](size_t bytes) -> void* {
        void* p = (void*)ws;
        ws += (bytes + 255) & ~(size_t)255;
        return p;
    };
    int*   cnt        = (int*)alloc((size_t)N * 4);
    int*   offsets    = (int*)alloc((size_t)(N + 1) * 4);
    int*   cursor     = (int*)alloc((size_t)N * 4);
    int*   sorted_src = (int*)alloc((size_t)E * 4);
    float* dinv       = (float*)alloc((size_t)N * 4);
    int*   psum       = (int*)alloc(256 * 4);
    int*   bpre       = (int*)alloc(256 * 4);
    int*   hist       = (int*)alloc(NBUCK * 4);
    int*   bcur       = (int*)alloc(NBUCK * 4);
    int*   perm       = (int*)alloc((size_t)N * 4);
    unsigned short* srcs16 = (unsigned short*)alloc((size_t)E * 2);

    const size_t slab_elems = (size_t)N * C;     // fp16 elements per k-slab
    const size_t slab_bytes = slab_elems * 2;    // 12.8 MB
    size_t misc_used = (size_t)(ws - (char*)d_ws);
    // deferred scheme keeps every k-slab: k = 0..K
    bool deferred = (ws_size >= misc_used + (size_t)(K + 1) * slab_bytes + 4096);
    uint4* Y4 = (uint4*)alloc((size_t)(deferred ? (K + 1) : 2) * slab_bytes);
    const size_t slab_u4 = slab_elems / 8;       // uint4 per k-slab (= N*16)

    const int B = 256;
    const int nb = (N + 255) / 256;              // 196 scan blocks (<= 256)
    const int nps = (N + NSLICE - 1) / NSLICE;   // 6250 nodes per slice
    const int slice_grid = 8 * 256;              // 8 slices x 256 chunks

    zero_cnt_kernel<<<(N + B - 1) / B, B, 0, stream>>>(cnt, N);
    count_kernel<<<slice_grid, B, 0, stream>>>(dst, cnt, E, nps);

    scan_reduce_kernel<<<nb, 256, 0, stream>>>(cnt, psum, N);
    scan_partials_kernel<<<1, 256, 0, stream>>>(psum, bpre, offsets, N, nb);
    scan_apply_kernel<<<nb, 256, 0, stream>>>(cnt, bpre, offsets, cursor, dinv, N);

    hist_zero_kernel<<<1, NBUCK, 0, stream>>>(hist);
    hist_kernel<<<64, 256, 0, stream>>>(cnt, hist, N);
    hist_scan_kernel<<<1, NBUCK, 0, stream>>>(hist, bcur);
    perm_kernel<<<nb, 256, 0, stream>>>(cnt, bcur, perm, N);

    scatter_kernel<<<slice_grid, B, 0, stream>>>(src, dst, cursor, sorted_src, E, nps);

    const bool use16 = (N <= 65536);
    if (use16) {
        int nvec = (E + 3) / 4;
        cvt_u16_kernel<<<(nvec + B - 1) / B, B, 0, stream>>>(sorted_src, srcs16, E);
    }

    float* hidden = (float*)d_out;
    float* hid_for_prop = deferred ? nullptr : hidden;
    init_kernel<<<((size_t)N * 16 + B - 1) / B, B, 0, stream>>>(
        x, coeffs, dinv, hid_for_prop, Y4, N);

    const int qblocks = (N + 63) / 64;                 // blocks per quarter
    const int grid4 = 8 * ((qblocks + 1) / 2);         // XCD-pair-partitioned grid
    for (int k = 1; k <= K; ++k) {
        int pin  = deferred ? (k - 1) : ((k - 1) & 1);
        int pout = deferred ? k       : (k & 1);
        if (use16) {
            prop4_kernel<unsigned short><<<grid4, B, 0, stream>>>(
                Y4 + (size_t)pin * slab_u4, Y4 + (size_t)pout * slab_u4,
                hid_for_prop, coeffs, k, offsets, srcs16, dinv, perm, N);
        } else {
            prop4_kernel<int><<<grid4, B, 0, stream>>>(
                Y4 + (size_t)pin * slab_u4, Y4 + (size_t)pout * slab_u4,
                hid_for_prop, coeffs, k, offsets, sorted_src, dinv, perm, N);
        }
    }

    if (deferred) {
        final_kernel<<<((size_t)N * 16 + B - 1) / B, B, 0, stream>>>(
            x, coeffs, dinv, Y4, hidden, N, K);
    }
}

// Round 4
// 619.017 us; speedup vs baseline: 1.5757x; 1.5757x over previous
//
#include <hip/hip_runtime.h>
#include <hip/hip_fp16.h>

#define C 128
#define HC 64      // channels per half
#define NBUCK 256
#define NSLICE 8
#define NCHUNK 512 // partition chunks (compile-time for pscan)
#define BCH 8      // count/scatter chunks per slice
#define MAXNPS 8192

typedef float f4_t __attribute__((ext_vector_type(4)));

// ======================= atomic-free preprocessing =========================
// A1: per-chunk per-slice edge counts (LDS atomics only)
__global__ __launch_bounds__(256)
void pcount_kernel(const int* __restrict__ dst, int* __restrict__ pcnt, int E, int nps) {
    int chunk = blockIdx.x;
    const int per = (E + NCHUNK - 1) / NCHUNK;
    int beg = chunk * per;
    int end = beg + per; if (end > E) end = E;
    __shared__ int lc[NSLICE];
    if (threadIdx.x < NSLICE) lc[threadIdx.x] = 0;
    __syncthreads();
    for (int e = beg + threadIdx.x; e < end; e += 256) {
        int s = dst[e] / nps;
        atomicAdd(&lc[s], 1);
    }
    __syncthreads();
    if (threadIdx.x < NSLICE) pcnt[chunk * NSLICE + threadIdx.x] = lc[threadIdx.x];
}

// A2: exclusive scan of 8*NCHUNK counts in slice-major order -> exact offsets
__global__ __launch_bounds__(256)
void pscan_kernel(const int* __restrict__ pcnt, int* __restrict__ poffs,
                  int* __restrict__ sbase, int E) {
    __shared__ int part[256];
    int t = threadIdx.x;
    int vals[16];
    int sum = 0;
    #pragma unroll
    for (int i = 0; i < 16; ++i) {
        int key = t * 16 + i;        // slice-major key = s*NCHUNK + c
        int s = key >> 9;            // / NCHUNK (512)
        int c = key & (NCHUNK - 1);
        vals[i] = pcnt[c * NSLICE + s];
        sum += vals[i];
    }
    part[t] = sum;
    __syncthreads();
    for (int off = 1; off < 256; off <<= 1) {
        int v = 0;
        if (t >= off) v = part[t - off];
        __syncthreads();
        if (t >= off) part[t] += v;
        __syncthreads();
    }
    int run = (t == 0) ? 0 : part[t - 1];
    #pragma unroll
    for (int i = 0; i < 16; ++i) {
        poffs[t * 16 + i] = run;
        run += vals[i];
    }
    __syncthreads();
    if (t < NSLICE) sbase[t] = poffs[t << 9];
    if (t == NSLICE) sbase[NSLICE] = E;
}

// A3: place edges into slice segments at exact positions (LDS cursors)
__global__ __launch_bounds__(256)
void ppart_kernel(const int* __restrict__ src, const int* __restrict__ dst,
                  const int* __restrict__ poffs, unsigned int* __restrict__ pedges,
                  int E, int nps) {
    int chunk = blockIdx.x;
    const int per = (E + NCHUNK - 1) / NCHUNK;
    int beg = chunk * per;
    int end = beg + per; if (end > E) end = E;
    __shared__ int lcur[NSLICE];
    if (threadIdx.x < NSLICE) lcur[threadIdx.x] = poffs[threadIdx.x * NCHUNK + chunk];
    __syncthreads();
    for (int e = beg + threadIdx.x; e < end; e += 256) {
        int d = dst[e];
        int s = d / nps;
        int pos = atomicAdd(&lcur[s], 1);
        pedges[pos] = ((unsigned)(d - s * nps) << 16) | (unsigned)src[e];
    }
}

// B: per-(slice,chunk) LDS histogram -> phist[c][node] (no global atomics)
__global__ __launch_bounds__(256)
void bcount_kernel(const unsigned int* __restrict__ pedges, const int* __restrict__ sbase,
                   int* __restrict__ phist, int N, int nps) {
    int s = blockIdx.x & 7;
    int c = blockIdx.x >> 3;
    int lo = sbase[s], hi = sbase[s + 1];
    int len = hi - lo;
    int per = (len + BCH - 1) / BCH;
    int beg = lo + c * per;
    int end = beg + per; if (end > hi) end = hi;
    __shared__ int h[MAXNPS];
    int base_node = s * nps;
    int nn = nps; if (base_node + nn > N) nn = N - base_node;
    for (int i = threadIdx.x; i < nn; i += 256) h[i] = 0;
    __syncthreads();
    for (int e = beg + threadIdx.x; e < end; e += 256) {
        unsigned int u = pedges[e];
        atomicAdd(&h[u >> 16], 1);
    }
    __syncthreads();
    int* out = phist + (size_t)c * N + base_node;
    for (int i = threadIdx.x; i < nn; i += 256) out[i] = h[i];
}

// merge1: cnt[i] = sum_c phist[c][i]
__global__ void merge1_kernel(const int* __restrict__ phist, int* __restrict__ cnt, int N) {
    int i = blockIdx.x * blockDim.x + threadIdx.x;
    if (i >= N) return;
    int s = 0;
    #pragma unroll
    for (int c = 0; c < BCH; ++c) s += phist[(size_t)c * N + i];
    cnt[i] = s;
}

// merge2: pbase[c][i] = offsets[i] + prefix_c(phist)
__global__ void merge2_kernel(const int* __restrict__ phist, const int* __restrict__ offsets,
                              int* __restrict__ pbase, int N) {
    int i = blockIdx.x * blockDim.x + threadIdx.x;
    if (i >= N) return;
    int run = offsets[i];
    #pragma unroll
    for (int c = 0; c < BCH; ++c) {
        pbase[(size_t)c * N + i] = run;
        run += phist[(size_t)c * N + i];
    }
}

// C: atomic-free CSR scatter -- LDS counting sort per (slice,chunk), u16 out
__global__ __launch_bounds__(256)
void pscatter_kernel(const unsigned int* __restrict__ pedges, const int* __restrict__ sbase,
                     const int* __restrict__ pbase, unsigned short* __restrict__ srcs16,
                     int N, int nps) {
    int s = blockIdx.x & 7;
    int c = blockIdx.x >> 3;
    int lo = sbase[s], hi = sbase[s + 1];
    int len = hi - lo;
    int per = (len + BCH - 1) / BCH;
    int beg = lo + c * per;
    int end = beg + per; if (end > hi) end = hi;
    __shared__ int lcur[MAXNPS];
    int base_node = s * nps;
    int nn = nps; if (base_node + nn > N) nn = N - base_node;
    const int* pb = pbase + (size_t)c * N + base_node;
    for (int i = threadIdx.x; i < nn; i += 256) lcur[i] = pb[i];
    __syncthreads();
    for (int e = beg + threadIdx.x; e < end; e += 256) {
        unsigned int u = pedges[e];
        int pos = atomicAdd(&lcur[u >> 16], 1);
        srcs16[pos] = (unsigned short)(u & 0xffffu);
    }
}

// ---- 3-phase parallel exclusive scan of cnt[0..n) --------------------------
__global__ void scan_reduce_kernel(const int* __restrict__ cnt, int* __restrict__ psum, int n) {
    __shared__ int s[256];
    int t = threadIdx.x;
    int i = blockIdx.x * 256 + t;
    s[t] = (i < n) ? cnt[i] : 0;
    __syncthreads();
    for (int off = 128; off > 0; off >>= 1) {
        if (t < off) s[t] += s[t + off];
        __syncthreads();
    }
    if (t == 0) psum[blockIdx.x] = s[0];
}

__global__ void scan_partials_kernel(const int* __restrict__ psum, int* __restrict__ bpre,
                                     int* __restrict__ offsets, int n, int nb) {
    __shared__ int s[256];
    int t = threadIdx.x;
    s[t] = (t < nb) ? psum[t] : 0;
    __syncthreads();
    for (int off = 1; off < 256; off <<= 1) {
        int v = 0;
        if (t >= off) v = s[t - off];
        __syncthreads();
        if (t >= off) s[t] += v;
        __syncthreads();
    }
    bpre[t] = (t == 0) ? 0 : s[t - 1];
    if (t == 255) offsets[n] = s[255];
}

__global__ void scan_apply_kernel(const int* __restrict__ cnt, const int* __restrict__ bpre,
                                  int* __restrict__ offsets, int* __restrict__ cursor,
                                  float* __restrict__ dinv, int n) {
    __shared__ int s[256];
    int t = threadIdx.x;
    int i = blockIdx.x * 256 + t;
    int c = (i < n) ? cnt[i] : 0;
    s[t] = c;
    __syncthreads();
    for (int off = 1; off < 256; off <<= 1) {
        int v = 0;
        if (t >= off) v = s[t - off];
        __syncthreads();
        if (t >= off) s[t] += v;
        __syncthreads();
    }
    if (i < n) {
        int excl = bpre[blockIdx.x] + s[t] - c;
        offsets[i] = excl;
        cursor[i]  = excl;
        dinv[i]    = rsqrtf((float)(c + 1));
    }
}

// ---- degree bucket sort -> perm (ascending degree) -------------------------
__global__ void hist_zero_kernel(int* __restrict__ hist) { hist[threadIdx.x] = 0; }

__global__ void hist_kernel(const int* __restrict__ cnt, int* __restrict__ hist, int n) {
    __shared__ int lh[NBUCK];
    int t = threadIdx.x;
    lh[t] = 0;
    __syncthreads();
    for (int i = blockIdx.x * blockDim.x + t; i < n; i += gridDim.x * blockDim.x) {
        int d = cnt[i]; if (d > NBUCK - 1) d = NBUCK - 1;
        atomicAdd(&lh[d], 1);
    }
    __syncthreads();
    int c = lh[t];
    if (c) atomicAdd(&hist[t], c);
}

__global__ void hist_scan_kernel(const int* __restrict__ hist, int* __restrict__ bcur) {
    __shared__ int s[256];
    int t = threadIdx.x;
    s[t] = hist[t];
    __syncthreads();
    for (int off = 1; off < 256; off <<= 1) {
        int v = 0;
        if (t >= off) v = s[t - off];
        __syncthreads();
        if (t >= off) s[t] += v;
        __syncthreads();
    }
    bcur[t] = (t == 0) ? 0 : s[t - 1];
}

__global__ void perm_kernel(const int* __restrict__ cnt, int* __restrict__ bcur,
                            int* __restrict__ perm, int n) {
    __shared__ int lhist[NBUCK];
    __shared__ int lbase[NBUCK];
    int t = threadIdx.x;
    lhist[t] = 0;
    __syncthreads();
    int i = blockIdx.x * 256 + t;
    int d = 0, lr = 0;
    if (i < n) {
        d = cnt[i]; if (d > NBUCK - 1) d = NBUCK - 1;
        lr = atomicAdd(&lhist[d], 1);
    }
    __syncthreads();
    int c = lhist[t];
    if (c > 0) lbase[t] = atomicAdd(&bcur[t], c);
    __syncthreads();
    if (i < n) perm[lbase[d] + lr] = i;
}

// ================= fallback preprocessing (N > 65536) ======================
__global__ void zero_cnt_kernel(int* __restrict__ cnt, int n) {
    int i = blockIdx.x * blockDim.x + threadIdx.x;
    if (i < n) cnt[i] = 0;
}

__global__ void count_kernel(const int* __restrict__ dst, int* __restrict__ cnt,
                             int E, int nps) {
    int slice = blockIdx.x & 7;
    int chunk = blockIdx.x >> 3;
    int nchunks = gridDim.x >> 3;
    int per = (E + nchunks - 1) / nchunks;
    int beg = chunk * per;
    int end = beg + per; if (end > E) end = E;
    int lo = slice * nps, hi = lo + nps;
    for (int e = beg + threadIdx.x; e < end; e += blockDim.x) {
        int d = dst[e];
        if (d >= lo && d < hi) atomicAdd(&cnt[d], 1);
    }
}

__global__ void scatter_kernel(const int* __restrict__ src, const int* __restrict__ dst,
                               int* __restrict__ cursor, int* __restrict__ sorted_src,
                               int E, int nps) {
    int slice = blockIdx.x & 7;
    int chunk = blockIdx.x >> 3;
    int nchunks = gridDim.x >> 3;
    int per = (E + nchunks - 1) / nchunks;
    int beg = chunk * per;
    int end = beg + per; if (end > E) end = E;
    int lo = slice * nps, hi = lo + nps;
    for (int e = beg + threadIdx.x; e < end; e += blockDim.x) {
        int d = dst[e];
        if (d >= lo && d < hi) {
            int pos = atomicAdd(&cursor[d], 1);
            sorted_src[pos] = src[e];
        }
    }
}

// ===================== propagation (round-1 verified) ======================
// y0 buffers: ya = half(dinv*x[:, 0:64]), yb = half(dinv*x[:, 64:128]).
__global__ void init_kernel(const float* __restrict__ x, const float* __restrict__ coeffs,
                            const float* __restrict__ dinv, float* __restrict__ hidden,
                            unsigned short* __restrict__ ya, unsigned short* __restrict__ yb,
                            int N) {
    int i = blockIdx.x * blockDim.x + threadIdx.x;   // over N*16 groups of 8 ch
    if (i >= N * 16) return;
    int node = i >> 4;
    int g = i & 15;            // 8-channel group within the 128-ch row
    float dv = dinv[node];
    const float4* xp = (const float4*)(x + (size_t)node * C + g * 8);
    float4 x0 = xp[0], x1 = xp[1];
    if (hidden) {
        float g0 = coeffs[0];
        float4* hp = (float4*)(hidden + (size_t)node * C + g * 8);
        hp[0] = make_float4(g0 * x0.x, g0 * x0.y, g0 * x0.z, g0 * x0.w);
        hp[1] = make_float4(g0 * x1.x, g0 * x1.y, g0 * x1.z, g0 * x1.w);
    }
    __half2 p0 = __floats2half2_rn(dv * x0.x, dv * x0.y);
    __half2 p1 = __floats2half2_rn(dv * x0.z, dv * x0.w);
    __half2 p2 = __floats2half2_rn(dv * x1.x, dv * x1.y);
    __half2 p3 = __floats2half2_rn(dv * x1.z, dv * x1.w);
    uint4 u;
    u.x = *reinterpret_cast<unsigned int*>(&p0);
    u.y = *reinterpret_cast<unsigned int*>(&p1);
    u.z = *reinterpret_cast<unsigned int*>(&p2);
    u.w = *reinterpret_cast<unsigned int*>(&p3);
    unsigned short* yp = (g < 8) ? ya : yb;
    int jj = g & 7;
    ((uint4*)yp)[(size_t)node * 8 + jj] = u;
}

__device__ __forceinline__ void acc8(float* a, uint4 u) {
    __half2* h = (__half2*)&u;
    #pragma unroll
    for (int i = 0; i < 4; ++i) {
        float2 f = __half22float2(h[i]);
        a[2 * i]     += f.x;
        a[2 * i + 1] += f.y;
    }
}

// merged-halves propagation step (half per XCD group), 128-B rows.
template<typename IdxT>
__global__ __launch_bounds__(256)
void prop2_kernel(const unsigned short* __restrict__ yin0, const unsigned short* __restrict__ yin1,
                  unsigned short* __restrict__ yout0, unsigned short* __restrict__ yout1,
                  float* __restrict__ hidden, const float* __restrict__ coeffs, int k,
                  const int* __restrict__ offsets, const IdxT* __restrict__ srcs,
                  const float* __restrict__ dinv, const int* __restrict__ perm, int n) {
    int bid  = blockIdx.x;
    int xcd  = bid & 7;            // assumes round-robin block->XCD (perf-only)
    int half = xcd >> 2;           // XCDs 0-3 -> half 0, XCDs 4-7 -> half 1
    int q    = (bid >> 3) * 4 + (xcd & 3);   // block index within the half
    int t = threadIdx.x;
    int lane = t & 63;
    int grp  = lane >> 3;          // node within wave: 0..7
    int j    = lane & 7;           // 16-B slice within 128-B half-row
    int slot = q * 32 + (t >> 6) * 8 + grp;
    if (slot >= n) return;
    int v = perm[slot];
    int beg = offsets[v];
    int end = offsets[v + 1];
    float dv = dinv[v];
    float gamma = coeffs[k];

    const uint4* base = (const uint4*)(half ? yin1 : yin0);  // row = 8 uint4
    float A0[8] = {0,0,0,0,0,0,0,0};
    float A1[8] = {0,0,0,0,0,0,0,0};
    float A2[8] = {0,0,0,0,0,0,0,0};
    float A3[8] = {0,0,0,0,0,0,0,0};

    int e = beg;
    for (; e + 8 <= end; e += 8) {
        int s0 = (int)srcs[e],     s1 = (int)srcs[e + 1];
        int s2 = (int)srcs[e + 2], s3 = (int)srcs[e + 3];
        int s4 = (int)srcs[e + 4], s5 = (int)srcs[e + 5];
        int s6 = (int)srcs[e + 6], s7 = (int)srcs[e + 7];
        uint4 u0 = base[(size_t)s0 * 8 + j];
        uint4 u1 = base[(size_t)s1 * 8 + j];
        uint4 u2 = base[(size_t)s2 * 8 + j];
        uint4 u3 = base[(size_t)s3 * 8 + j];
        uint4 u4 = base[(size_t)s4 * 8 + j];
        uint4 u5 = base[(size_t)s5 * 8 + j];
        uint4 u6 = base[(size_t)s6 * 8 + j];
        uint4 u7 = base[(size_t)s7 * 8 + j];
        acc8(A0, u0); acc8(A1, u1); acc8(A2, u2); acc8(A3, u3);
        acc8(A0, u4); acc8(A1, u5); acc8(A2, u6); acc8(A3, u7);
    }
    for (; e + 4 <= end; e += 4) {
        int s0 = (int)srcs[e],     s1 = (int)srcs[e + 1];
        int s2 = (int)srcs[e + 2], s3 = (int)srcs[e + 3];
        uint4 u0 = base[(size_t)s0 * 8 + j];
        uint4 u1 = base[(size_t)s1 * 8 + j];
        uint4 u2 = base[(size_t)s2 * 8 + j];
        uint4 u3 = base[(size_t)s3 * 8 + j];
        acc8(A0, u0); acc8(A1, u1); acc8(A2, u2); acc8(A3, u3);
    }
    for (; e < end; ++e) {
        uint4 u = base[(size_t)srcs[e] * 8 + j];
        acc8(A0, u);
    }
    // self-loop term
    uint4 us = base[(size_t)v * 8 + j];
    acc8(A1, us);

    float xn[8];
    #pragma unroll
    for (int i = 0; i < 8; ++i)
        xn[i] = dv * ((A0[i] + A1[i]) + (A2[i] + A3[i]));

    if (hidden) {
        // fallback scheme: per-step RMW (nontemporal to protect y residency)
        f4_t* hp = (f4_t*)(hidden + (size_t)v * C + half * HC + j * 8);
        f4_t h0 = __builtin_nontemporal_load(hp);
        f4_t h1 = __builtin_nontemporal_load(hp + 1);
        h0.x += gamma * xn[0]; h0.y += gamma * xn[1]; h0.z += gamma * xn[2]; h0.w += gamma * xn[3];
        h1.x += gamma * xn[4]; h1.y += gamma * xn[5]; h1.z += gamma * xn[6]; h1.w += gamma * xn[7];
        __builtin_nontemporal_store(h0, hp);
        __builtin_nontemporal_store(h1, hp + 1);
    }

    // yout = half(dinv * xn)
    __half2 p0 = __floats2half2_rn(dv * xn[0], dv * xn[1]);
    __half2 p1 = __floats2half2_rn(dv * xn[2], dv * xn[3]);
    __half2 p2 = __floats2half2_rn(dv * xn[4], dv * xn[5]);
    __half2 p3 = __floats2half2_rn(dv * xn[6], dv * xn[7]);
    uint4 u;
    u.x = *reinterpret_cast<unsigned int*>(&p0);
    u.y = *reinterpret_cast<unsigned int*>(&p1);
    u.z = *reinterpret_cast<unsigned int*>(&p2);
    u.w = *reinterpret_cast<unsigned int*>(&p3);
    unsigned short* yout = half ? yout1 : yout0;
    ((uint4*)yout)[(size_t)v * 8 + j] = u;
}

// deferred hidden build: hidden = coeffs[0]*x + sum_k coeffs[k] * y_k / dinv.
__global__ void final_kernel(const float* __restrict__ x, const float* __restrict__ coeffs,
                             const float* __restrict__ dinv, const unsigned short* __restrict__ ybig,
                             float* __restrict__ hidden, int N, int K) {
    int i = blockIdx.x * blockDim.x + threadIdx.x;
    if (i >= N * 16) return;
    int node = i >> 4;
    int g = i & 15;
    int half = g >> 3;
    int jj = g & 7;
    float g0 = coeffs[0];
    float rdv = 1.0f / dinv[node];           // = sqrt(deg+1)
    const float4* xp = (const float4*)(x + (size_t)node * C + g * 8);
    float4 x0 = xp[0], x1 = xp[1];
    float a[8] = {g0 * x0.x, g0 * x0.y, g0 * x0.z, g0 * x0.w,
                  g0 * x1.x, g0 * x1.y, g0 * x1.z, g0 * x1.w};
    const uint4* yb = (const uint4*)ybig;
    size_t bstride = (size_t)N * 8;          // uint4 per buffer
    size_t row = (size_t)node * 8 + jj;
    for (int k = 1; k <= K; ++k) {
        float s = coeffs[k] * rdv;
        uint4 u = yb[(size_t)(2 * k + half) * bstride + row];
        __half2* h = (__half2*)&u;
        #pragma unroll
        for (int q2 = 0; q2 < 4; ++q2) {
            float2 f = __half22float2(h[q2]);
            a[2 * q2]     += s * f.x;
            a[2 * q2 + 1] += s * f.y;
        }
    }
    float4* hp = (float4*)(hidden + (size_t)node * C + g * 8);
    hp[0] = make_float4(a[0], a[1], a[2], a[3]);
    hp[1] = make_float4(a[4], a[5], a[6], a[7]);
}

extern "C" void kernel_launch(void* const* d_in, const int* in_sizes, int n_in,
                              void* d_out, int out_size, void* d_ws, size_t ws_size,
                              hipStream_t stream) {
    const float* x      = (const float*)d_in[0];
    const float* coeffs = (const float*)d_in[1];
    const int*   edge   = (const int*)d_in[2];

    const int N = in_sizes[0] / C;          // 50000
    const int K = in_sizes[1] - 1;          // 10
    const int E = in_sizes[2] / 2;          // 1,600,000
    const int* src = edge;
    const int* dst = edge + E;

    char* ws = (char*)d_ws;
    auto alloc = [&](size_t bytes) -> void* {
        void* p = (void*)ws;
        ws += (bytes + 255) & ~(size_t)255;
        return p;
    };
    int*   cnt        = (int*)alloc((size_t)N * 4);
    int*   offsets    = (int*)alloc((size_t)(N + 1) * 4);
    int*   cursor     = (int*)alloc((size_t)N * 4);
    int*   sorted_src = (int*)alloc((size_t)E * 4);       // fallback path only
    float* dinv       = (float*)alloc((size_t)N * 4);
    int*   psum       = (int*)alloc(256 * 4);
    int*   bpre       = (int*)alloc(256 * 4);
    int*   hist       = (int*)alloc(NBUCK * 4);
    int*   bcur       = (int*)alloc(NBUCK * 4);
    int*   perm       = (int*)alloc((size_t)N * 4);
    unsigned short* srcs16 = (unsigned short*)alloc((size_t)E * 2);
    unsigned int*   pedges = (unsigned int*)alloc((size_t)E * 4);
    int*   pcnt   = (int*)alloc((size_t)NCHUNK * NSLICE * 4);
    int*   poffs  = (int*)alloc((size_t)NCHUNK * NSLICE * 4);
    int*   sbase  = (int*)alloc((NSLICE + 1) * 4);
    int*   phist  = (int*)alloc((size_t)BCH * N * 4);
    int*   pbase  = (int*)alloc((size_t)BCH * N * 4);

    const size_t NBelems  = (size_t)N * HC;     // elements per y half-buffer
    const size_t bufbytes = NBelems * 2;        // fp16
    size_t misc_used = (size_t)(ws - (char*)d_ws);
    const int nbuf_deferred = 2 * (K + 1);      // both halves, k = 0..K
    bool deferred = (ws_size >= misc_used + (size_t)nbuf_deferred * bufbytes + 4096);
    unsigned short* ybig = (unsigned short*)alloc((size_t)(deferred ? nbuf_deferred : 4) * bufbytes);
    auto ybuf = [&](int p, int h) -> unsigned short* {
        return ybig + ((size_t)(2 * p + h)) * NBelems;
    };

    const int B = 256;
    const int nb = (N + 255) / 256;
    const int nps = (N + NSLICE - 1) / NSLICE;   // 6250
    const bool fastpre = (N <= 65536) && (nps <= MAXNPS);

    if (fastpre) {
        // atomic-free preprocessing
        pcount_kernel<<<NCHUNK, B, 0, stream>>>(dst, pcnt, E, nps);
        pscan_kernel<<<1, B, 0, stream>>>(pcnt, poffs, sbase, E);
        ppart_kernel<<<NCHUNK, B, 0, stream>>>(src, dst, poffs, pedges, E, nps);
        bcount_kernel<<<8 * BCH, B, 0, stream>>>(pedges, sbase, phist, N, nps);
        merge1_kernel<<<nb, B, 0, stream>>>(phist, cnt, N);
        scan_reduce_kernel<<<nb, 256, 0, stream>>>(cnt, psum, N);
        scan_partials_kernel<<<1, 256, 0, stream>>>(psum, bpre, offsets, N, nb);
        scan_apply_kernel<<<nb, 256, 0, stream>>>(cnt, bpre, offsets, cursor, dinv, N);
        merge2_kernel<<<nb, B, 0, stream>>>(phist, offsets, pbase, N);
        hist_zero_kernel<<<1, NBUCK, 0, stream>>>(hist);
        hist_kernel<<<64, 256, 0, stream>>>(cnt, hist, N);
        hist_scan_kernel<<<1, NBUCK, 0, stream>>>(hist, bcur);
        perm_kernel<<<nb, 256, 0, stream>>>(cnt, bcur, perm, N);
        pscatter_kernel<<<8 * BCH, B, 0, stream>>>(pedges, sbase, pbase, srcs16, N, nps);
    } else {
        const int slice_grid = 8 * 256;
        zero_cnt_kernel<<<(N + B - 1) / B, B, 0, stream>>>(cnt, N);
        count_kernel<<<slice_grid, B, 0, stream>>>(dst, cnt, E, nps);
        scan_reduce_kernel<<<nb, 256, 0, stream>>>(cnt, psum, N);
        scan_partials_kernel<<<1, 256, 0, stream>>>(psum, bpre, offsets, N, nb);
        scan_apply_kernel<<<nb, 256, 0, stream>>>(cnt, bpre, offsets, cursor, dinv, N);
        hist_zero_kernel<<<1, NBUCK, 0, stream>>>(hist);
        hist_kernel<<<64, 256, 0, stream>>>(cnt, hist, N);
        hist_scan_kernel<<<1, NBUCK, 0, stream>>>(hist, bcur);
        perm_kernel<<<nb, 256, 0, stream>>>(cnt, bcur, perm, N);
        scatter_kernel<<<slice_grid, B, 0, stream>>>(src, dst, cursor, sorted_src, E, nps);
    }

    float* hidden = (float*)d_out;
    float* hid_for_prop = deferred ? nullptr : hidden;
    init_kernel<<<((size_t)N * 16 + B - 1) / B, B, 0, stream>>>(
        x, coeffs, dinv, hid_for_prop, ybuf(0, 0), ybuf(0, 1), N);

    const int pgrid = (N + 31) / 32;                 // blocks per half
    const int grid2 = 8 * ((pgrid + 3) / 4);         // XCD-partitioned merged grid
    for (int k = 1; k <= K; ++k) {
        int pin  = deferred ? (k - 1) : ((k - 1) & 1);
        int pout = deferred ? k       : (k & 1);
        if (fastpre) {
            prop2_kernel<unsigned short><<<grid2, B, 0, stream>>>(
                ybuf(pin, 0), ybuf(pin, 1), ybuf(pout, 0), ybuf(pout, 1),
                hid_for_prop, coeffs, k, offsets, srcs16, dinv, perm, N);
        } else {
            prop2_kernel<int><<<grid2, B, 0, stream>>>(
                ybuf(pin, 0), ybuf(pin, 1), ybuf(pout, 0), ybuf(pout, 1),
                hid_for_prop, coeffs, k, offsets, sorted_src, dinv, perm, N);
        }
    }

    if (deferred) {
        final_kernel<<<((size_t)N * 16 + B - 1) / B, B, 0, stream>>>(
            x, coeffs, dinv, ybig, hidden, N, K);
    }
}

// Round 5
// 588.230 us; speedup vs baseline: 1.6581x; 1.0523x over previous
//
#include <hip/hip_runtime.h>
#include <hip/hip_fp16.h>

#define C 128
#define HC 64      // channels per half
#define NBUCK 256
#define NSLICE 8
#define NCHUNK 512 // partition chunks (compile-time for pscan)
#define BCH 64     // count/scatter chunks per slice (8*BCH blocks total)
#define MAXNPS 8192

typedef float f4_t __attribute__((ext_vector_type(4)));

// ======================= atomic-free preprocessing =========================
// A1: per-chunk per-slice edge counts (LDS atomics only)
__global__ __launch_bounds__(256)
void pcount_kernel(const int* __restrict__ dst, int* __restrict__ pcnt, int E, int nps) {
    int chunk = blockIdx.x;
    const int per = (E + NCHUNK - 1) / NCHUNK;
    int beg = chunk * per;
    int end = beg + per; if (end > E) end = E;
    __shared__ int lc[NSLICE];
    if (threadIdx.x < NSLICE) lc[threadIdx.x] = 0;
    __syncthreads();
    for (int e = beg + threadIdx.x; e < end; e += 256) {
        int s = dst[e] / nps;
        atomicAdd(&lc[s], 1);
    }
    __syncthreads();
    if (threadIdx.x < NSLICE) pcnt[chunk * NSLICE + threadIdx.x] = lc[threadIdx.x];
}

// A2: exclusive scan of 8*NCHUNK counts in slice-major order -> exact offsets
__global__ __launch_bounds__(256)
void pscan_kernel(const int* __restrict__ pcnt, int* __restrict__ poffs,
                  int* __restrict__ sbase, int E) {
    __shared__ int part[256];
    int t = threadIdx.x;
    int vals[16];
    int sum = 0;
    #pragma unroll
    for (int i = 0; i < 16; ++i) {
        int key = t * 16 + i;        // slice-major key = s*NCHUNK + c
        int s = key >> 9;            // / NCHUNK (512)
        int c = key & (NCHUNK - 1);
        vals[i] = pcnt[c * NSLICE + s];
        sum += vals[i];
    }
    part[t] = sum;
    __syncthreads();
    for (int off = 1; off < 256; off <<= 1) {
        int v = 0;
        if (t >= off) v = part[t - off];
        __syncthreads();
        if (t >= off) part[t] += v;
        __syncthreads();
    }
    int run = (t == 0) ? 0 : part[t - 1];
    #pragma unroll
    for (int i = 0; i < 16; ++i) {
        poffs[t * 16 + i] = run;
        run += vals[i];
    }
    __syncthreads();
    if (t < NSLICE) sbase[t] = poffs[t << 9];
    if (t == NSLICE) sbase[NSLICE] = E;
}

// A3: place edges into slice segments at exact positions (LDS cursors)
__global__ __launch_bounds__(256)
void ppart_kernel(const int* __restrict__ src, const int* __restrict__ dst,
                  const int* __restrict__ poffs, unsigned int* __restrict__ pedges,
                  int E, int nps) {
    int chunk = blockIdx.x;
    const int per = (E + NCHUNK - 1) / NCHUNK;
    int beg = chunk * per;
    int end = beg + per; if (end > E) end = E;
    __shared__ int lcur[NSLICE];
    if (threadIdx.x < NSLICE) lcur[threadIdx.x] = poffs[threadIdx.x * NCHUNK + chunk];
    __syncthreads();
    for (int e = beg + threadIdx.x; e < end; e += 256) {
        int d = dst[e];
        int s = d / nps;
        int pos = atomicAdd(&lcur[s], 1);
        pedges[pos] = ((unsigned)(d - s * nps) << 16) | (unsigned)src[e];
    }
}

// B: per-(slice,chunk) LDS histogram -> phist[c][node] (no global atomics)
__global__ __launch_bounds__(256)
void bcount_kernel(const unsigned int* __restrict__ pedges, const int* __restrict__ sbase,
                   int* __restrict__ phist, int N, int nps) {
    int s = blockIdx.x & 7;
    int c = blockIdx.x >> 3;
    int lo = sbase[s], hi = sbase[s + 1];
    int len = hi - lo;
    int per = (len + BCH - 1) / BCH;
    int beg = lo + c * per;
    int end = beg + per; if (end > hi) end = hi;
    __shared__ int h[MAXNPS];
    int base_node = s * nps;
    int nn = nps; if (base_node + nn > N) nn = N - base_node;
    for (int i = threadIdx.x; i < nn; i += 256) h[i] = 0;
    __syncthreads();
    for (int e = beg + threadIdx.x; e < end; e += 256) {
        unsigned int u = pedges[e];
        atomicAdd(&h[u >> 16], 1);
    }
    __syncthreads();
    int* out = phist + (size_t)c * N + base_node;
    for (int i = threadIdx.x; i < nn; i += 256) out[i] = h[i];
}

// merge1: cnt[i] = sum_c phist[c][i]
__global__ void merge1_kernel(const int* __restrict__ phist, int* __restrict__ cnt, int N) {
    int i = blockIdx.x * blockDim.x + threadIdx.x;
    if (i >= N) return;
    int s = 0;
    #pragma unroll 8
    for (int c = 0; c < BCH; ++c) s += phist[(size_t)c * N + i];
    cnt[i] = s;
}

// merge2: pbase[c][i] = offsets[i] + prefix_c(phist)
__global__ void merge2_kernel(const int* __restrict__ phist, const int* __restrict__ offsets,
                              int* __restrict__ pbase, int N) {
    int i = blockIdx.x * blockDim.x + threadIdx.x;
    if (i >= N) return;
    int run = offsets[i];
    #pragma unroll 8
    for (int c = 0; c < BCH; ++c) {
        pbase[(size_t)c * N + i] = run;
        run += phist[(size_t)c * N + i];
    }
}

// C: atomic-free CSR scatter -- LDS counting sort per (slice,chunk), u16 out
__global__ __launch_bounds__(256)
void pscatter_kernel(const unsigned int* __restrict__ pedges, const int* __restrict__ sbase,
                     const int* __restrict__ pbase, unsigned short* __restrict__ srcs16,
                     int N, int nps) {
    int s = blockIdx.x & 7;
    int c = blockIdx.x >> 3;
    int lo = sbase[s], hi = sbase[s + 1];
    int len = hi - lo;
    int per = (len + BCH - 1) / BCH;
    int beg = lo + c * per;
    int end = beg + per; if (end > hi) end = hi;
    __shared__ int lcur[MAXNPS];
    int base_node = s * nps;
    int nn = nps; if (base_node + nn > N) nn = N - base_node;
    const int* pb = pbase + (size_t)c * N + base_node;
    for (int i = threadIdx.x; i < nn; i += 256) lcur[i] = pb[i];
    __syncthreads();
    for (int e = beg + threadIdx.x; e < end; e += 256) {
        unsigned int u = pedges[e];
        int pos = atomicAdd(&lcur[u >> 16], 1);
        srcs16[pos] = (unsigned short)(u & 0xffffu);
    }
}

// ---- 3-phase parallel exclusive scan of cnt[0..n) --------------------------
__global__ void scan_reduce_kernel(const int* __restrict__ cnt, int* __restrict__ psum, int n) {
    __shared__ int s[256];
    int t = threadIdx.x;
    int i = blockIdx.x * 256 + t;
    s[t] = (i < n) ? cnt[i] : 0;
    __syncthreads();
    for (int off = 128; off > 0; off >>= 1) {
        if (t < off) s[t] += s[t + off];
        __syncthreads();
    }
    if (t == 0) psum[blockIdx.x] = s[0];
}

__global__ void scan_partials_kernel(const int* __restrict__ psum, int* __restrict__ bpre,
                                     int* __restrict__ offsets, int n, int nb) {
    __shared__ int s[256];
    int t = threadIdx.x;
    s[t] = (t < nb) ? psum[t] : 0;
    __syncthreads();
    for (int off = 1; off < 256; off <<= 1) {
        int v = 0;
        if (t >= off) v = s[t - off];
        __syncthreads();
        if (t >= off) s[t] += v;
        __syncthreads();
    }
    bpre[t] = (t == 0) ? 0 : s[t - 1];
    if (t == 255) offsets[n] = s[255];
}

__global__ void scan_apply_kernel(const int* __restrict__ cnt, const int* __restrict__ bpre,
                                  int* __restrict__ offsets, int* __restrict__ cursor,
                                  float* __restrict__ dinv, int n) {
    __shared__ int s[256];
    int t = threadIdx.x;
    int i = blockIdx.x * 256 + t;
    int c = (i < n) ? cnt[i] : 0;
    s[t] = c;
    __syncthreads();
    for (int off = 1; off < 256; off <<= 1) {
        int v = 0;
        if (t >= off) v = s[t - off];
        __syncthreads();
        if (t >= off) s[t] += v;
        __syncthreads();
    }
    if (i < n) {
        int excl = bpre[blockIdx.x] + s[t] - c;
        offsets[i] = excl;
        cursor[i]  = excl;
        dinv[i]    = rsqrtf((float)(c + 1));
    }
}

// ---- degree bucket sort -> perm (ascending degree) -------------------------
__global__ void hist_zero_kernel(int* __restrict__ hist) { hist[threadIdx.x] = 0; }

__global__ void hist_kernel(const int* __restrict__ cnt, int* __restrict__ hist, int n) {
    __shared__ int lh[NBUCK];
    int t = threadIdx.x;
    lh[t] = 0;
    __syncthreads();
    for (int i = blockIdx.x * blockDim.x + t; i < n; i += gridDim.x * blockDim.x) {
        int d = cnt[i]; if (d > NBUCK - 1) d = NBUCK - 1;
        atomicAdd(&lh[d], 1);
    }
    __syncthreads();
    int c = lh[t];
    if (c) atomicAdd(&hist[t], c);
}

__global__ void hist_scan_kernel(const int* __restrict__ hist, int* __restrict__ bcur) {
    __shared__ int s[256];
    int t = threadIdx.x;
    s[t] = hist[t];
    __syncthreads();
    for (int off = 1; off < 256; off <<= 1) {
        int v = 0;
        if (t >= off) v = s[t - off];
        __syncthreads();
        if (t >= off) s[t] += v;
        __syncthreads();
    }
    bcur[t] = (t == 0) ? 0 : s[t - 1];
}

__global__ void perm_kernel(const int* __restrict__ cnt, int* __restrict__ bcur,
                            int* __restrict__ perm, int n) {
    __shared__ int lhist[NBUCK];
    __shared__ int lbase[NBUCK];
    int t = threadIdx.x;
    lhist[t] = 0;
    __syncthreads();
    int i = blockIdx.x * 256 + t;
    int d = 0, lr = 0;
    if (i < n) {
        d = cnt[i]; if (d > NBUCK - 1) d = NBUCK - 1;
        lr = atomicAdd(&lhist[d], 1);
    }
    __syncthreads();
    int c = lhist[t];
    if (c > 0) lbase[t] = atomicAdd(&bcur[t], c);
    __syncthreads();
    if (i < n) perm[lbase[d] + lr] = i;
}

// ================= fallback preprocessing (N > 65536) ======================
__global__ void zero_cnt_kernel(int* __restrict__ cnt, int n) {
    int i = blockIdx.x * blockDim.x + threadIdx.x;
    if (i < n) cnt[i] = 0;
}

__global__ void count_kernel(const int* __restrict__ dst, int* __restrict__ cnt,
                             int E, int nps) {
    int slice = blockIdx.x & 7;
    int chunk = blockIdx.x >> 3;
    int nchunks = gridDim.x >> 3;
    int per = (E + nchunks - 1) / nchunks;
    int beg = chunk * per;
    int end = beg + per; if (end > E) end = E;
    int lo = slice * nps, hi = lo + nps;
    for (int e = beg + threadIdx.x; e < end; e += blockDim.x) {
        int d = dst[e];
        if (d >= lo && d < hi) atomicAdd(&cnt[d], 1);
    }
}

__global__ void scatter_kernel(const int* __restrict__ src, const int* __restrict__ dst,
                               int* __restrict__ cursor, int* __restrict__ sorted_src,
                               int E, int nps) {
    int slice = blockIdx.x & 7;
    int chunk = blockIdx.x >> 3;
    int nchunks = gridDim.x >> 3;
    int per = (E + nchunks - 1) / nchunks;
    int beg = chunk * per;
    int end = beg + per; if (end > E) end = E;
    int lo = slice * nps, hi = lo + nps;
    for (int e = beg + threadIdx.x; e < end; e += blockDim.x) {
        int d = dst[e];
        if (d >= lo && d < hi) {
            int pos = atomicAdd(&cursor[d], 1);
            sorted_src[pos] = src[e];
        }
    }
}

// ===================== propagation (round-1 verified) ======================
// y0 buffers: ya = half(dinv*x[:, 0:64]), yb = half(dinv*x[:, 64:128]).
__global__ void init_kernel(const float* __restrict__ x, const float* __restrict__ coeffs,
                            const float* __restrict__ dinv, float* __restrict__ hidden,
                            unsigned short* __restrict__ ya, unsigned short* __restrict__ yb,
                            int N) {
    int i = blockIdx.x * blockDim.x + threadIdx.x;   // over N*16 groups of 8 ch
    if (i >= N * 16) return;
    int node = i >> 4;
    int g = i & 15;            // 8-channel group within the 128-ch row
    float dv = dinv[node];
    const float4* xp = (const float4*)(x + (size_t)node * C + g * 8);
    float4 x0 = xp[0], x1 = xp[1];
    if (hidden) {
        float g0 = coeffs[0];
        float4* hp = (float4*)(hidden + (size_t)node * C + g * 8);
        hp[0] = make_float4(g0 * x0.x, g0 * x0.y, g0 * x0.z, g0 * x0.w);
        hp[1] = make_float4(g0 * x1.x, g0 * x1.y, g0 * x1.z, g0 * x1.w);
    }
    __half2 p0 = __floats2half2_rn(dv * x0.x, dv * x0.y);
    __half2 p1 = __floats2half2_rn(dv * x0.z, dv * x0.w);
    __half2 p2 = __floats2half2_rn(dv * x1.x, dv * x1.y);
    __half2 p3 = __floats2half2_rn(dv * x1.z, dv * x1.w);
    uint4 u;
    u.x = *reinterpret_cast<unsigned int*>(&p0);
    u.y = *reinterpret_cast<unsigned int*>(&p1);
    u.z = *reinterpret_cast<unsigned int*>(&p2);
    u.w = *reinterpret_cast<unsigned int*>(&p3);
    unsigned short* yp = (g < 8) ? ya : yb;
    int jj = g & 7;
    ((uint4*)yp)[(size_t)node * 8 + jj] = u;
}

__device__ __forceinline__ void acc8(float* a, uint4 u) {
    __half2* h = (__half2*)&u;
    #pragma unroll
    for (int i = 0; i < 4; ++i) {
        float2 f = __half22float2(h[i]);
        a[2 * i]     += f.x;
        a[2 * i + 1] += f.y;
    }
}

// merged-halves propagation step (half per XCD group), 128-B rows.
template<typename IdxT>
__global__ __launch_bounds__(256)
void prop2_kernel(const unsigned short* __restrict__ yin0, const unsigned short* __restrict__ yin1,
                  unsigned short* __restrict__ yout0, unsigned short* __restrict__ yout1,
                  float* __restrict__ hidden, const float* __restrict__ coeffs, int k,
                  const int* __restrict__ offsets, const IdxT* __restrict__ srcs,
                  const float* __restrict__ dinv, const int* __restrict__ perm, int n) {
    int bid  = blockIdx.x;
    int xcd  = bid & 7;            // assumes round-robin block->XCD (perf-only)
    int half = xcd >> 2;           // XCDs 0-3 -> half 0, XCDs 4-7 -> half 1
    int q    = (bid >> 3) * 4 + (xcd & 3);   // block index within the half
    int t = threadIdx.x;
    int lane = t & 63;
    int grp  = lane >> 3;          // node within wave: 0..7
    int j    = lane & 7;           // 16-B slice within 128-B half-row
    int slot = q * 32 + (t >> 6) * 8 + grp;
    if (slot >= n) return;
    int v = perm[slot];
    int beg = offsets[v];
    int end = offsets[v + 1];
    float dv = dinv[v];
    float gamma = coeffs[k];

    const uint4* base = (const uint4*)(half ? yin1 : yin0);  // row = 8 uint4
    float A0[8] = {0,0,0,0,0,0,0,0};
    float A1[8] = {0,0,0,0,0,0,0,0};
    float A2[8] = {0,0,0,0,0,0,0,0};
    float A3[8] = {0,0,0,0,0,0,0,0};

    int e = beg;
    for (; e + 8 <= end; e += 8) {
        int s0 = (int)srcs[e],     s1 = (int)srcs[e + 1];
        int s2 = (int)srcs[e + 2], s3 = (int)srcs[e + 3];
        int s4 = (int)srcs[e + 4], s5 = (int)srcs[e + 5];
        int s6 = (int)srcs[e + 6], s7 = (int)srcs[e + 7];
        uint4 u0 = base[(size_t)s0 * 8 + j];
        uint4 u1 = base[(size_t)s1 * 8 + j];
        uint4 u2 = base[(size_t)s2 * 8 + j];
        uint4 u3 = base[(size_t)s3 * 8 + j];
        uint4 u4 = base[(size_t)s4 * 8 + j];
        uint4 u5 = base[(size_t)s5 * 8 + j];
        uint4 u6 = base[(size_t)s6 * 8 + j];
        uint4 u7 = base[(size_t)s7 * 8 + j];
        acc8(A0, u0); acc8(A1, u1); acc8(A2, u2); acc8(A3, u3);
        acc8(A0, u4); acc8(A1, u5); acc8(A2, u6); acc8(A3, u7);
    }
    for (; e + 4 <= end; e += 4) {
        int s0 = (int)srcs[e],     s1 = (int)srcs[e + 1];
        int s2 = (int)srcs[e + 2], s3 = (int)srcs[e + 3];
        uint4 u0 = base[(size_t)s0 * 8 + j];
        uint4 u1 = base[(size_t)s1 * 8 + j];
        uint4 u2 = base[(size_t)s2 * 8 + j];
        uint4 u3 = base[(size_t)s3 * 8 + j];
        acc8(A0, u0); acc8(A1, u1); acc8(A2, u2); acc8(A3, u3);
    }
    for (; e < end; ++e) {
        uint4 u = base[(size_t)srcs[e] * 8 + j];
        acc8(A0, u);
    }
    // self-loop term
    uint4 us = base[(size_t)v * 8 + j];
    acc8(A1, us);

    float xn[8];
    #pragma unroll
    for (int i = 0; i < 8; ++i)
        xn[i] = dv * ((A0[i] + A1[i]) + (A2[i] + A3[i]));

    if (hidden) {
        // fallback scheme: per-step RMW (nontemporal to protect y residency)
        f4_t* hp = (f4_t*)(hidden + (size_t)v * C + half * HC + j * 8);
        f4_t h0 = __builtin_nontemporal_load(hp);
        f4_t h1 = __builtin_nontemporal_load(hp + 1);
        h0.x += gamma * xn[0]; h0.y += gamma * xn[1]; h0.z += gamma * xn[2]; h0.w += gamma * xn[3];
        h1.x += gamma * xn[4]; h1.y += gamma * xn[5]; h1.z += gamma * xn[6]; h1.w += gamma * xn[7];
        __builtin_nontemporal_store(h0, hp);
        __builtin_nontemporal_store(h1, hp + 1);
    }

    // yout = half(dinv * xn)
    __half2 p0 = __floats2half2_rn(dv * xn[0], dv * xn[1]);
    __half2 p1 = __floats2half2_rn(dv * xn[2], dv * xn[3]);
    __half2 p2 = __floats2half2_rn(dv * xn[4], dv * xn[5]);
    __half2 p3 = __floats2half2_rn(dv * xn[6], dv * xn[7]);
    uint4 u;
    u.x = *reinterpret_cast<unsigned int*>(&p0);
    u.y = *reinterpret_cast<unsigned int*>(&p1);
    u.z = *reinterpret_cast<unsigned int*>(&p2);
    u.w = *reinterpret_cast<unsigned int*>(&p3);
    unsigned short* yout = half ? yout1 : yout0;
    ((uint4*)yout)[(size_t)v * 8 + j] = u;
}

// deferred hidden build: hidden = coeffs[0]*x + sum_k coeffs[k] * y_k / dinv.
__global__ void final_kernel(const float* __restrict__ x, const float* __restrict__ coeffs,
                             const float* __restrict__ dinv, const unsigned short* __restrict__ ybig,
                             float* __restrict__ hidden, int N, int K) {
    int i = blockIdx.x * blockDim.x + threadIdx.x;
    if (i >= N * 16) return;
    int node = i >> 4;
    int g = i & 15;
    int half = g >> 3;
    int jj = g & 7;
    float g0 = coeffs[0];
    float rdv = 1.0f / dinv[node];           // = sqrt(deg+1)
    const float4* xp = (const float4*)(x + (size_t)node * C + g * 8);
    float4 x0 = xp[0], x1 = xp[1];
    float a[8] = {g0 * x0.x, g0 * x0.y, g0 * x0.z, g0 * x0.w,
                  g0 * x1.x, g0 * x1.y, g0 * x1.z, g0 * x1.w};
    const uint4* yb = (const uint4*)ybig;
    size_t bstride = (size_t)N * 8;          // uint4 per buffer
    size_t row = (size_t)node * 8 + jj;
    for (int k = 1; k <= K; ++k) {
        float s = coeffs[k] * rdv;
        uint4 u = yb[(size_t)(2 * k + half) * bstride + row];
        __half2* h = (__half2*)&u;
        #pragma unroll
        for (int q2 = 0; q2 < 4; ++q2) {
            float2 f = __half22float2(h[q2]);
            a[2 * q2]     += s * f.x;
            a[2 * q2 + 1] += s * f.y;
        }
    }
    float4* hp = (float4*)(hidden + (size_t)node * C + g * 8);
    hp[0] = make_float4(a[0], a[1], a[2], a[3]);
    hp[1] = make_float4(a[4], a[5], a[6], a[7]);
}

extern "C" void kernel_launch(void* const* d_in, const int* in_sizes, int n_in,
                              void* d_out, int out_size, void* d_ws, size_t ws_size,
                              hipStream_t stream) {
    const float* x      = (const float*)d_in[0];
    const float* coeffs = (const float*)d_in[1];
    const int*   edge   = (const int*)d_in[2];

    const int N = in_sizes[0] / C;          // 50000
    const int K = in_sizes[1] - 1;          // 10
    const int E = in_sizes[2] / 2;          // 1,600,000
    const int* src = edge;
    const int* dst = edge + E;

    char* ws = (char*)d_ws;
    auto alloc = [&](size_t bytes) -> void* {
        void* p = (void*)ws;
        ws += (bytes + 255) & ~(size_t)255;
        return p;
    };
    int*   cnt        = (int*)alloc((size_t)N * 4);
    int*   offsets    = (int*)alloc((size_t)(N + 1) * 4);
    int*   cursor     = (int*)alloc((size_t)N * 4);
    int*   sorted_src = (int*)alloc((size_t)E * 4);       // fallback path only
    float* dinv       = (float*)alloc((size_t)N * 4);
    int*   psum       = (int*)alloc(256 * 4);
    int*   bpre       = (int*)alloc(256 * 4);
    int*   hist       = (int*)alloc(NBUCK * 4);
    int*   bcur       = (int*)alloc(NBUCK * 4);
    int*   perm       = (int*)alloc((size_t)N * 4);
    unsigned short* srcs16 = (unsigned short*)alloc((size_t)E * 2);
    unsigned int*   pedges = (unsigned int*)alloc((size_t)E * 4);
    int*   pcnt   = (int*)alloc((size_t)NCHUNK * NSLICE * 4);
    int*   poffs  = (int*)alloc((size_t)NCHUNK * NSLICE * 4);
    int*   sbase  = (int*)alloc((NSLICE + 1) * 4);
    int*   phist  = (int*)alloc((size_t)BCH * N * 4);
    int*   pbase  = (int*)alloc((size_t)BCH * N * 4);

    const size_t NBelems  = (size_t)N * HC;     // elements per y half-buffer
    const size_t bufbytes = NBelems * 2;        // fp16
    size_t misc_used = (size_t)(ws - (char*)d_ws);
    const int nbuf_deferred = 2 * (K + 1);      // both halves, k = 0..K
    bool deferred = (ws_size >= misc_used + (size_t)nbuf_deferred * bufbytes + 4096);
    unsigned short* ybig = (unsigned short*)alloc((size_t)(deferred ? nbuf_deferred : 4) * bufbytes);
    auto ybuf = [&](int p, int h) -> unsigned short* {
        return ybig + ((size_t)(2 * p + h)) * NBelems;
    };

    const int B = 256;
    const int nb = (N + 255) / 256;
    const int nps = (N + NSLICE - 1) / NSLICE;   // 6250
    const bool fastpre = (N <= 65536) && (nps <= MAXNPS);

    if (fastpre) {
        // atomic-free preprocessing
        pcount_kernel<<<NCHUNK, B, 0, stream>>>(dst, pcnt, E, nps);
        pscan_kernel<<<1, B, 0, stream>>>(pcnt, poffs, sbase, E);
        ppart_kernel<<<NCHUNK, B, 0, stream>>>(src, dst, poffs, pedges, E, nps);
        bcount_kernel<<<8 * BCH, B, 0, stream>>>(pedges, sbase, phist, N, nps);
        merge1_kernel<<<nb, B, 0, stream>>>(phist, cnt, N);
        scan_reduce_kernel<<<nb, 256, 0, stream>>>(cnt, psum, N);
        scan_partials_kernel<<<1, 256, 0, stream>>>(psum, bpre, offsets, N, nb);
        scan_apply_kernel<<<nb, 256, 0, stream>>>(cnt, bpre, offsets, cursor, dinv, N);
        merge2_kernel<<<nb, B, 0, stream>>>(phist, offsets, pbase, N);
        hist_zero_kernel<<<1, NBUCK, 0, stream>>>(hist);
        hist_kernel<<<64, 256, 0, stream>>>(cnt, hist, N);
        hist_scan_kernel<<<1, NBUCK, 0, stream>>>(hist, bcur);
        perm_kernel<<<nb, 256, 0, stream>>>(cnt, bcur, perm, N);
        pscatter_kernel<<<8 * BCH, B, 0, stream>>>(pedges, sbase, pbase, srcs16, N, nps);
    } else {
        const int slice_grid = 8 * 256;
        zero_cnt_kernel<<<(N + B - 1) / B, B, 0, stream>>>(cnt, N);
        count_kernel<<<slice_grid, B, 0, stream>>>(dst, cnt, E, nps);
        scan_reduce_kernel<<<nb, 256, 0, stream>>>(cnt, psum, N);
        scan_partials_kernel<<<1, 256, 0, stream>>>(psum, bpre, offsets, N, nb);
        scan_apply_kernel<<<nb, 256, 0, stream>>>(cnt, bpre, offsets, cursor, dinv, N);
        hist_zero_kernel<<<1, NBUCK, 0, stream>>>(hist);
        hist_kernel<<<64, 256, 0, stream>>>(cnt, hist, N);
        hist_scan_kernel<<<1, NBUCK, 0, stream>>>(hist, bcur);
        perm_kernel<<<nb, 256, 0, stream>>>(cnt, bcur, perm, N);
        scatter_kernel<<<slice_grid, B, 0, stream>>>(src, dst, cursor, sorted_src, E, nps);
    }

    float* hidden = (float*)d_out;
    float* hid_for_prop = deferred ? nullptr : hidden;
    init_kernel<<<((size_t)N * 16 + B - 1) / B, B, 0, stream>>>(
        x, coeffs, dinv, hid_for_prop, ybuf(0, 0), ybuf(0, 1), N);

    const int pgrid = (N + 31) / 32;                 // blocks per half
    const int grid2 = 8 * ((pgrid + 3) / 4);         // XCD-partitioned merged grid
    for (int k = 1; k <= K; ++k) {
        int pin  = deferred ? (k - 1) : ((k - 1) & 1);
        int pout = deferred ? k       : (k & 1);
        if (fastpre) {
            prop2_kernel<unsigned short><<<grid2, B, 0, stream>>>(
                ybuf(pin, 0), ybuf(pin, 1), ybuf(pout, 0), ybuf(pout, 1),
                hid_for_prop, coeffs, k, offsets, srcs16, dinv, perm, N);
        } else {
            prop2_kernel<int><<<grid2, B, 0, stream>>>(
                ybuf(pin, 0), ybuf(pin, 1), ybuf(pout, 0), ybuf(pout, 1),
                hid_for_prop, coeffs, k, offsets, sorted_src, dinv, perm, N);
        }
    }

    if (deferred) {
        final_kernel<<<((size_t)N * 16 + B - 1) / B, B, 0, stream>>>(
            x, coeffs, dinv, ybig, hidden, N, K);
    }
}

// Round 6
// 541.591 us; speedup vs baseline: 1.8009x; 1.0861x over previous
//
#include <hip/hip_runtime.h>
#include <hip/hip_fp16.h>

#define C 128
#define HC 64      // channels per half
#define NBUCK 256
#define NSLICE 8
#define NCHUNK 512 // partition chunks (compile-time for pscan)
#define BCH 64     // count/scatter chunks per slice (8*BCH blocks total)
#define MAXNPS 8192

typedef float f4_t __attribute__((ext_vector_type(4)));

// ======================= atomic-free preprocessing =========================
// Pass 0: partition edges by SRC-octant so every dst adjacency list ends up
// src-banded (chunk-stable downstream sorts preserve this order). Gives the
// prop gather an ~800 KB instantaneous working set (fits 4 MB XCD L2).

// S0a: per-chunk per-src-octant counts (LDS atomics only)
__global__ __launch_bounds__(256)
void s0count_kernel(const int* __restrict__ src, int* __restrict__ s0cnt, int E, int snps) {
    int chunk = blockIdx.x;
    const int per = (E + NCHUNK - 1) / NCHUNK;
    int beg = chunk * per;
    int end = beg + per; if (end > E) end = E;
    __shared__ int lc[NSLICE];
    if (threadIdx.x < NSLICE) lc[threadIdx.x] = 0;
    __syncthreads();
    for (int e = beg + threadIdx.x; e < end; e += 256) {
        int s = src[e] / snps;
        atomicAdd(&lc[s], 1);
    }
    __syncthreads();
    if (threadIdx.x < NSLICE) s0cnt[chunk * NSLICE + threadIdx.x] = lc[threadIdx.x];
}

// S0b: place edges into src-octant segments, packed (dst<<16)|src (global ids)
__global__ __launch_bounds__(256)
void s0part_kernel(const int* __restrict__ src, const int* __restrict__ dst,
                   const int* __restrict__ s0offs, unsigned int* __restrict__ edges0,
                   int E, int snps) {
    int chunk = blockIdx.x;
    const int per = (E + NCHUNK - 1) / NCHUNK;
    int beg = chunk * per;
    int end = beg + per; if (end > E) end = E;
    __shared__ int lcur[NSLICE];
    if (threadIdx.x < NSLICE) lcur[threadIdx.x] = s0offs[threadIdx.x * NCHUNK + chunk];
    __syncthreads();
    for (int e = beg + threadIdx.x; e < end; e += 256) {
        int sv = src[e];
        int s = sv / snps;
        int pos = atomicAdd(&lcur[s], 1);
        edges0[pos] = ((unsigned)dst[e] << 16) | (unsigned)sv;
    }
}

// A2: exclusive scan of 8*NCHUNK counts in slice-major order -> exact offsets
__global__ __launch_bounds__(256)
void pscan_kernel(const int* __restrict__ pcnt, int* __restrict__ poffs,
                  int* __restrict__ sbase, int E) {
    __shared__ int part[256];
    int t = threadIdx.x;
    int vals[16];
    int sum = 0;
    #pragma unroll
    for (int i = 0; i < 16; ++i) {
        int key = t * 16 + i;        // slice-major key = s*NCHUNK + c
        int s = key >> 9;            // / NCHUNK (512)
        int c = key & (NCHUNK - 1);
        vals[i] = pcnt[c * NSLICE + s];
        sum += vals[i];
    }
    part[t] = sum;
    __syncthreads();
    for (int off = 1; off < 256; off <<= 1) {
        int v = 0;
        if (t >= off) v = part[t - off];
        __syncthreads();
        if (t >= off) part[t] += v;
        __syncthreads();
    }
    int run = (t == 0) ? 0 : part[t - 1];
    #pragma unroll
    for (int i = 0; i < 16; ++i) {
        poffs[t * 16 + i] = run;
        run += vals[i];
    }
    __syncthreads();
    if (t < NSLICE) sbase[t] = poffs[t << 9];
    if (t == NSLICE) sbase[NSLICE] = E;
}

// A1: per-chunk per-dst-slice counts over packed edges0 (src-octant-ordered)
__global__ __launch_bounds__(256)
void pcount2_kernel(const unsigned int* __restrict__ edges0, int* __restrict__ pcnt,
                    int E, int nps) {
    int chunk = blockIdx.x;
    const int per = (E + NCHUNK - 1) / NCHUNK;
    int beg = chunk * per;
    int end = beg + per; if (end > E) end = E;
    __shared__ int lc[NSLICE];
    if (threadIdx.x < NSLICE) lc[threadIdx.x] = 0;
    __syncthreads();
    for (int e = beg + threadIdx.x; e < end; e += 256) {
        int s = (int)(edges0[e] >> 16) / nps;
        atomicAdd(&lc[s], 1);
    }
    __syncthreads();
    if (threadIdx.x < NSLICE) pcnt[chunk * NSLICE + threadIdx.x] = lc[threadIdx.x];
}

// A3: place edges into dst-slice segments (chunk-stable -> keeps src-banding)
__global__ __launch_bounds__(256)
void ppart2_kernel(const unsigned int* __restrict__ edges0, const int* __restrict__ poffs,
                   unsigned int* __restrict__ pedges, int E, int nps) {
    int chunk = blockIdx.x;
    const int per = (E + NCHUNK - 1) / NCHUNK;
    int beg = chunk * per;
    int end = beg + per; if (end > E) end = E;
    __shared__ int lcur[NSLICE];
    if (threadIdx.x < NSLICE) lcur[threadIdx.x] = poffs[threadIdx.x * NCHUNK + chunk];
    __syncthreads();
    for (int e = beg + threadIdx.x; e < end; e += 256) {
        unsigned int u = edges0[e];
        int d = (int)(u >> 16);
        int s = d / nps;
        int pos = atomicAdd(&lcur[s], 1);
        pedges[pos] = ((unsigned)(d - s * nps) << 16) | (u & 0xffffu);
    }
}

// B: per-(slice,chunk) LDS histogram -> phist[c][node] (no global atomics)
__global__ __launch_bounds__(256)
void bcount_kernel(const unsigned int* __restrict__ pedges, const int* __restrict__ sbase,
                   int* __restrict__ phist, int N, int nps) {
    int s = blockIdx.x & 7;
    int c = blockIdx.x >> 3;
    int lo = sbase[s], hi = sbase[s + 1];
    int len = hi - lo;
    int per = (len + BCH - 1) / BCH;
    int beg = lo + c * per;
    int end = beg + per; if (end > hi) end = hi;
    __shared__ int h[MAXNPS];
    int base_node = s * nps;
    int nn = nps; if (base_node + nn > N) nn = N - base_node;
    for (int i = threadIdx.x; i < nn; i += 256) h[i] = 0;
    __syncthreads();
    for (int e = beg + threadIdx.x; e < end; e += 256) {
        unsigned int u = pedges[e];
        atomicAdd(&h[u >> 16], 1);
    }
    __syncthreads();
    int* out = phist + (size_t)c * N + base_node;
    for (int i = threadIdx.x; i < nn; i += 256) out[i] = h[i];
}

// merge1: cnt[i] = sum_c phist[c][i]
__global__ void merge1_kernel(const int* __restrict__ phist, int* __restrict__ cnt, int N) {
    int i = blockIdx.x * blockDim.x + threadIdx.x;
    if (i >= N) return;
    int s = 0;
    #pragma unroll 8
    for (int c = 0; c < BCH; ++c) s += phist[(size_t)c * N + i];
    cnt[i] = s;
}

// merge2: pbase[c][i] = offsets[i] + prefix_c(phist)
__global__ void merge2_kernel(const int* __restrict__ phist, const int* __restrict__ offsets,
                              int* __restrict__ pbase, int N) {
    int i = blockIdx.x * blockDim.x + threadIdx.x;
    if (i >= N) return;
    int run = offsets[i];
    #pragma unroll 8
    for (int c = 0; c < BCH; ++c) {
        pbase[(size_t)c * N + i] = run;
        run += phist[(size_t)c * N + i];
    }
}

// C: atomic-free CSR scatter -- LDS counting sort per (slice,chunk), u16 out
__global__ __launch_bounds__(256)
void pscatter_kernel(const unsigned int* __restrict__ pedges, const int* __restrict__ sbase,
                     const int* __restrict__ pbase, unsigned short* __restrict__ srcs16,
                     int N, int nps) {
    int s = blockIdx.x & 7;
    int c = blockIdx.x >> 3;
    int lo = sbase[s], hi = sbase[s + 1];
    int len = hi - lo;
    int per = (len + BCH - 1) / BCH;
    int beg = lo + c * per;
    int end = beg + per; if (end > hi) end = hi;
    __shared__ int lcur[MAXNPS];
    int base_node = s * nps;
    int nn = nps; if (base_node + nn > N) nn = N - base_node;
    const int* pb = pbase + (size_t)c * N + base_node;
    for (int i = threadIdx.x; i < nn; i += 256) lcur[i] = pb[i];
    __syncthreads();
    for (int e = beg + threadIdx.x; e < end; e += 256) {
        unsigned int u = pedges[e];
        int pos = atomicAdd(&lcur[u >> 16], 1);
        srcs16[pos] = (unsigned short)(u & 0xffffu);
    }
}

// ---- 3-phase parallel exclusive scan of cnt[0..n) --------------------------
__global__ void scan_reduce_kernel(const int* __restrict__ cnt, int* __restrict__ psum, int n) {
    __shared__ int s[256];
    int t = threadIdx.x;
    int i = blockIdx.x * 256 + t;
    s[t] = (i < n) ? cnt[i] : 0;
    __syncthreads();
    for (int off = 128; off > 0; off >>= 1) {
        if (t < off) s[t] += s[t + off];
        __syncthreads();
    }
    if (t == 0) psum[blockIdx.x] = s[0];
}

__global__ void scan_partials_kernel(const int* __restrict__ psum, int* __restrict__ bpre,
                                     int* __restrict__ offsets, int n, int nb) {
    __shared__ int s[256];
    int t = threadIdx.x;
    s[t] = (t < nb) ? psum[t] : 0;
    __syncthreads();
    for (int off = 1; off < 256; off <<= 1) {
        int v = 0;
        if (t >= off) v = s[t - off];
        __syncthreads();
        if (t >= off) s[t] += v;
        __syncthreads();
    }
    bpre[t] = (t == 0) ? 0 : s[t - 1];
    if (t == 255) offsets[n] = s[255];
}

__global__ void scan_apply_kernel(const int* __restrict__ cnt, const int* __restrict__ bpre,
                                  int* __restrict__ offsets, int* __restrict__ cursor,
                                  float* __restrict__ dinv, int n) {
    __shared__ int s[256];
    int t = threadIdx.x;
    int i = blockIdx.x * 256 + t;
    int c = (i < n) ? cnt[i] : 0;
    s[t] = c;
    __syncthreads();
    for (int off = 1; off < 256; off <<= 1) {
        int v = 0;
        if (t >= off) v = s[t - off];
        __syncthreads();
        if (t >= off) s[t] += v;
        __syncthreads();
    }
    if (i < n) {
        int excl = bpre[blockIdx.x] + s[t] - c;
        offsets[i] = excl;
        cursor[i]  = excl;
        dinv[i]    = rsqrtf((float)(c + 1));
    }
}

// ---- degree bucket sort -> perm (DESCENDING degree: LPT scheduling) --------
__global__ void hist_zero_kernel(int* __restrict__ hist) { hist[threadIdx.x] = 0; }

__global__ void hist_kernel(const int* __restrict__ cnt, int* __restrict__ hist, int n) {
    __shared__ int lh[NBUCK];
    int t = threadIdx.x;
    lh[t] = 0;
    __syncthreads();
    for (int i = blockIdx.x * blockDim.x + t; i < n; i += gridDim.x * blockDim.x) {
        int d = cnt[i]; if (d > NBUCK - 1) d = NBUCK - 1;
        atomicAdd(&lh[d], 1);
    }
    __syncthreads();
    int c = lh[t];
    if (c) atomicAdd(&hist[t], c);
}

// base for bucket d = sum of counts of buckets > d (descending layout)
__global__ void hist_scan_kernel(const int* __restrict__ hist, int* __restrict__ bcur) {
    __shared__ int s[256];
    int t = threadIdx.x;
    s[t] = hist[t];
    __syncthreads();
    for (int off = 1; off < 256; off <<= 1) {
        int v = 0;
        if (t >= off) v = s[t - off];
        __syncthreads();
        if (t >= off) s[t] += v;
        __syncthreads();
    }
    int total = s[255];
    bcur[t] = total - s[t];      // suffix sum: buckets > t come first
}

__global__ void perm_kernel(const int* __restrict__ cnt, int* __restrict__ bcur,
                            int* __restrict__ perm, int n) {
    __shared__ int lhist[NBUCK];
    __shared__ int lbase[NBUCK];
    int t = threadIdx.x;
    lhist[t] = 0;
    __syncthreads();
    int i = blockIdx.x * 256 + t;
    int d = 0, lr = 0;
    if (i < n) {
        d = cnt[i]; if (d > NBUCK - 1) d = NBUCK - 1;
        lr = atomicAdd(&lhist[d], 1);
    }
    __syncthreads();
    int c = lhist[t];
    if (c > 0) lbase[t] = atomicAdd(&bcur[t], c);
    __syncthreads();
    if (i < n) perm[lbase[d] + lr] = i;
}

// ================= fallback preprocessing (N > 65536) ======================
__global__ void zero_cnt_kernel(int* __restrict__ cnt, int n) {
    int i = blockIdx.x * blockDim.x + threadIdx.x;
    if (i < n) cnt[i] = 0;
}

__global__ void count_kernel(const int* __restrict__ dst, int* __restrict__ cnt,
                             int E, int nps) {
    int slice = blockIdx.x & 7;
    int chunk = blockIdx.x >> 3;
    int nchunks = gridDim.x >> 3;
    int per = (E + nchunks - 1) / nchunks;
    int beg = chunk * per;
    int end = beg + per; if (end > E) end = E;
    int lo = slice * nps, hi = lo + nps;
    for (int e = beg + threadIdx.x; e < end; e += blockDim.x) {
        int d = dst[e];
        if (d >= lo && d < hi) atomicAdd(&cnt[d], 1);
    }
}

__global__ void scatter_kernel(const int* __restrict__ src, const int* __restrict__ dst,
                               int* __restrict__ cursor, int* __restrict__ sorted_src,
                               int E, int nps) {
    int slice = blockIdx.x & 7;
    int chunk = blockIdx.x >> 3;
    int nchunks = gridDim.x >> 3;
    int per = (E + nchunks - 1) / nchunks;
    int beg = chunk * per;
    int end = beg + per; if (end > E) end = E;
    int lo = slice * nps, hi = lo + nps;
    for (int e = beg + threadIdx.x; e < end; e += blockDim.x) {
        int d = dst[e];
        if (d >= lo && d < hi) {
            int pos = atomicAdd(&cursor[d], 1);
            sorted_src[pos] = src[e];
        }
    }
}

// ===================== propagation (round-1 verified) ======================
// y0 buffers: ya = half(dinv*x[:, 0:64]), yb = half(dinv*x[:, 64:128]).
__global__ void init_kernel(const float* __restrict__ x, const float* __restrict__ coeffs,
                            const float* __restrict__ dinv, float* __restrict__ hidden,
                            unsigned short* __restrict__ ya, unsigned short* __restrict__ yb,
                            int N) {
    int i = blockIdx.x * blockDim.x + threadIdx.x;   // over N*16 groups of 8 ch
    if (i >= N * 16) return;
    int node = i >> 4;
    int g = i & 15;            // 8-channel group within the 128-ch row
    float dv = dinv[node];
    const float4* xp = (const float4*)(x + (size_t)node * C + g * 8);
    float4 x0 = xp[0], x1 = xp[1];
    if (hidden) {
        float g0 = coeffs[0];
        float4* hp = (float4*)(hidden + (size_t)node * C + g * 8);
        hp[0] = make_float4(g0 * x0.x, g0 * x0.y, g0 * x0.z, g0 * x0.w);
        hp[1] = make_float4(g0 * x1.x, g0 * x1.y, g0 * x1.z, g0 * x1.w);
    }
    __half2 p0 = __floats2half2_rn(dv * x0.x, dv * x0.y);
    __half2 p1 = __floats2half2_rn(dv * x0.z, dv * x0.w);
    __half2 p2 = __floats2half2_rn(dv * x1.x, dv * x1.y);
    __half2 p3 = __floats2half2_rn(dv * x1.z, dv * x1.w);
    uint4 u;
    u.x = *reinterpret_cast<unsigned int*>(&p0);
    u.y = *reinterpret_cast<unsigned int*>(&p1);
    u.z = *reinterpret_cast<unsigned int*>(&p2);
    u.w = *reinterpret_cast<unsigned int*>(&p3);
    unsigned short* yp = (g < 8) ? ya : yb;
    int jj = g & 7;
    ((uint4*)yp)[(size_t)node * 8 + jj] = u;
}

__device__ __forceinline__ void acc8(float* a, uint4 u) {
    __half2* h = (__half2*)&u;
    #pragma unroll
    for (int i = 0; i < 4; ++i) {
        float2 f = __half22float2(h[i]);
        a[2 * i]     += f.x;
        a[2 * i + 1] += f.y;
    }
}

// merged-halves propagation step (half per XCD group), 128-B rows.
template<typename IdxT>
__global__ __launch_bounds__(256)
void prop2_kernel(const unsigned short* __restrict__ yin0, const unsigned short* __restrict__ yin1,
                  unsigned short* __restrict__ yout0, unsigned short* __restrict__ yout1,
                  float* __restrict__ hidden, const float* __restrict__ coeffs, int k,
                  const int* __restrict__ offsets, const IdxT* __restrict__ srcs,
                  const float* __restrict__ dinv, const int* __restrict__ perm, int n) {
    int bid  = blockIdx.x;
    int xcd  = bid & 7;            // assumes round-robin block->XCD (perf-only)
    int half = xcd >> 2;           // XCDs 0-3 -> half 0, XCDs 4-7 -> half 1
    int q    = (bid >> 3) * 4 + (xcd & 3);   // block index within the half
    int t = threadIdx.x;
    int lane = t & 63;
    int grp  = lane >> 3;          // node within wave: 0..7
    int j    = lane & 7;           // 16-B slice within 128-B half-row
    int slot = q * 32 + (t >> 6) * 8 + grp;
    if (slot >= n) return;
    int v = perm[slot];
    int beg = offsets[v];
    int end = offsets[v + 1];
    float dv = dinv[v];
    float gamma = coeffs[k];

    const uint4* base = (const uint4*)(half ? yin1 : yin0);  // row = 8 uint4
    float A0[8] = {0,0,0,0,0,0,0,0};
    float A1[8] = {0,0,0,0,0,0,0,0};
    float A2[8] = {0,0,0,0,0,0,0,0};
    float A3[8] = {0,0,0,0,0,0,0,0};

    int e = beg;
    for (; e + 8 <= end; e += 8) {
        int s0 = (int)srcs[e],     s1 = (int)srcs[e + 1];
        int s2 = (int)srcs[e + 2], s3 = (int)srcs[e + 3];
        int s4 = (int)srcs[e + 4], s5 = (int)srcs[e + 5];
        int s6 = (int)srcs[e + 6], s7 = (int)srcs[e + 7];
        uint4 u0 = base[(size_t)s0 * 8 + j];
        uint4 u1 = base[(size_t)s1 * 8 + j];
        uint4 u2 = base[(size_t)s2 * 8 + j];
        uint4 u3 = base[(size_t)s3 * 8 + j];
        uint4 u4 = base[(size_t)s4 * 8 + j];
        uint4 u5 = base[(size_t)s5 * 8 + j];
        uint4 u6 = base[(size_t)s6 * 8 + j];
        uint4 u7 = base[(size_t)s7 * 8 + j];
        acc8(A0, u0); acc8(A1, u1); acc8(A2, u2); acc8(A3, u3);
        acc8(A0, u4); acc8(A1, u5); acc8(A2, u6); acc8(A3, u7);
    }
    for (; e + 4 <= end; e += 4) {
        int s0 = (int)srcs[e],     s1 = (int)srcs[e + 1];
        int s2 = (int)srcs[e + 2], s3 = (int)srcs[e + 3];
        uint4 u0 = base[(size_t)s0 * 8 + j];
        uint4 u1 = base[(size_t)s1 * 8 + j];
        uint4 u2 = base[(size_t)s2 * 8 + j];
        uint4 u3 = base[(size_t)s3 * 8 + j];
        acc8(A0, u0); acc8(A1, u1); acc8(A2, u2); acc8(A3, u3);
    }
    for (; e < end; ++e) {
        uint4 u = base[(size_t)srcs[e] * 8 + j];
        acc8(A0, u);
    }
    // self-loop term
    uint4 us = base[(size_t)v * 8 + j];
    acc8(A1, us);

    float xn[8];
    #pragma unroll
    for (int i = 0; i < 8; ++i)
        xn[i] = dv * ((A0[i] + A1[i]) + (A2[i] + A3[i]));

    if (hidden) {
        // fallback scheme: per-step RMW (nontemporal to protect y residency)
        f4_t* hp = (f4_t*)(hidden + (size_t)v * C + half * HC + j * 8);
        f4_t h0 = __builtin_nontemporal_load(hp);
        f4_t h1 = __builtin_nontemporal_load(hp + 1);
        h0.x += gamma * xn[0]; h0.y += gamma * xn[1]; h0.z += gamma * xn[2]; h0.w += gamma * xn[3];
        h1.x += gamma * xn[4]; h1.y += gamma * xn[5]; h1.z += gamma * xn[6]; h1.w += gamma * xn[7];
        __builtin_nontemporal_store(h0, hp);
        __builtin_nontemporal_store(h1, hp + 1);
    }

    // yout = half(dinv * xn)
    __half2 p0 = __floats2half2_rn(dv * xn[0], dv * xn[1]);
    __half2 p1 = __floats2half2_rn(dv * xn[2], dv * xn[3]);
    __half2 p2 = __floats2half2_rn(dv * xn[4], dv * xn[5]);
    __half2 p3 = __floats2half2_rn(dv * xn[6], dv * xn[7]);
    uint4 u;
    u.x = *reinterpret_cast<unsigned int*>(&p0);
    u.y = *reinterpret_cast<unsigned int*>(&p1);
    u.z = *reinterpret_cast<unsigned int*>(&p2);
    u.w = *reinterpret_cast<unsigned int*>(&p3);
    unsigned short* yout = half ? yout1 : yout0;
    ((uint4*)yout)[(size_t)v * 8 + j] = u;
}

// deferred hidden build: hidden = coeffs[0]*x + sum_k coeffs[k] * y_k / dinv.
__global__ void final_kernel(const float* __restrict__ x, const float* __restrict__ coeffs,
                             const float* __restrict__ dinv, const unsigned short* __restrict__ ybig,
                             float* __restrict__ hidden, int N, int K) {
    int i = blockIdx.x * blockDim.x + threadIdx.x;
    if (i >= N * 16) return;
    int node = i >> 4;
    int g = i & 15;
    int half = g >> 3;
    int jj = g & 7;
    float g0 = coeffs[0];
    float rdv = 1.0f / dinv[node];           // = sqrt(deg+1)
    const float4* xp = (const float4*)(x + (size_t)node * C + g * 8);
    float4 x0 = xp[0], x1 = xp[1];
    float a[8] = {g0 * x0.x, g0 * x0.y, g0 * x0.z, g0 * x0.w,
                  g0 * x1.x, g0 * x1.y, g0 * x1.z, g0 * x1.w};
    const uint4* yb = (const uint4*)ybig;
    size_t bstride = (size_t)N * 8;          // uint4 per buffer
    size_t row = (size_t)node * 8 + jj;
    for (int k = 1; k <= K; ++k) {
        float s = coeffs[k] * rdv;
        uint4 u = yb[(size_t)(2 * k + half) * bstride + row];
        __half2* h = (__half2*)&u;
        #pragma unroll
        for (int q2 = 0; q2 < 4; ++q2) {
            float2 f = __half22float2(h[q2]);
            a[2 * q2]     += s * f.x;
            a[2 * q2 + 1] += s * f.y;
        }
    }
    float4* hp = (float4*)(hidden + (size_t)node * C + g * 8);
    hp[0] = make_float4(a[0], a[1], a[2], a[3]);
    hp[1] = make_float4(a[4], a[5], a[6], a[7]);
}

extern "C" void kernel_launch(void* const* d_in, const int* in_sizes, int n_in,
                              void* d_out, int out_size, void* d_ws, size_t ws_size,
                              hipStream_t stream) {
    const float* x      = (const float*)d_in[0];
    const float* coeffs = (const float*)d_in[1];
    const int*   edge   = (const int*)d_in[2];

    const int N = in_sizes[0] / C;          // 50000
    const int K = in_sizes[1] - 1;          // 10
    const int E = in_sizes[2] / 2;          // 1,600,000
    const int* src = edge;
    const int* dst = edge + E;

    char* ws = (char*)d_ws;
    auto alloc = [&](size_t bytes) -> void* {
        void* p = (void*)ws;
        ws += (bytes + 255) & ~(size_t)255;
        return p;
    };
    int*   cnt        = (int*)alloc((size_t)N * 4);
    int*   offsets    = (int*)alloc((size_t)(N + 1) * 4);
    int*   cursor     = (int*)alloc((size_t)N * 4);
    int*   sorted_src = (int*)alloc((size_t)E * 4);       // fallback path only
    float* dinv       = (float*)alloc((size_t)N * 4);
    int*   psum       = (int*)alloc(256 * 4);
    int*   bpre       = (int*)alloc(256 * 4);
    int*   hist       = (int*)alloc(NBUCK * 4);
    int*   bcur       = (int*)alloc(NBUCK * 4);
    int*   perm       = (int*)alloc((size_t)N * 4);
    unsigned short* srcs16 = (unsigned short*)alloc((size_t)E * 2);
    unsigned int*   pedges = (unsigned int*)alloc((size_t)E * 4);
    unsigned int*   edges0 = (unsigned int*)alloc((size_t)E * 4);
    int*   pcnt   = (int*)alloc((size_t)NCHUNK * NSLICE * 4);
    int*   poffs  = (int*)alloc((size_t)NCHUNK * NSLICE * 4);
    int*   sbase  = (int*)alloc((NSLICE + 1) * 4);
    int*   s0cnt  = (int*)alloc((size_t)NCHUNK * NSLICE * 4);
    int*   s0offs = (int*)alloc((size_t)NCHUNK * NSLICE * 4);
    int*   s0base = (int*)alloc((NSLICE + 1) * 4);
    int*   phist  = (int*)alloc((size_t)BCH * N * 4);
    int*   pbase  = (int*)alloc((size_t)BCH * N * 4);

    const size_t NBelems  = (size_t)N * HC;     // elements per y half-buffer
    const size_t bufbytes = NBelems * 2;        // fp16
    size_t misc_used = (size_t)(ws - (char*)d_ws);
    const int nbuf_deferred = 2 * (K + 1);      // both halves, k = 0..K
    bool deferred = (ws_size >= misc_used + (size_t)nbuf_deferred * bufbytes + 4096);
    unsigned short* ybig = (unsigned short*)alloc((size_t)(deferred ? nbuf_deferred : 4) * bufbytes);
    auto ybuf = [&](int p, int h) -> unsigned short* {
        return ybig + ((size_t)(2 * p + h)) * NBelems;
    };

    const int B = 256;
    const int nb = (N + 255) / 256;
    const int nps = (N + NSLICE - 1) / NSLICE;   // 6250
    const int snps = nps;                        // src-octant size
    const bool fastpre = (N <= 65536) && (nps <= MAXNPS);

    if (fastpre) {
        // Pass 0: partition by src-octant (banded gather locality in prop)
        s0count_kernel<<<NCHUNK, B, 0, stream>>>(src, s0cnt, E, snps);
        pscan_kernel<<<1, B, 0, stream>>>(s0cnt, s0offs, s0base, E);
        s0part_kernel<<<NCHUNK, B, 0, stream>>>(src, dst, s0offs, edges0, E, snps);
        // dst-slice partition (chunk-stable -> preserves src-banding)
        pcount2_kernel<<<NCHUNK, B, 0, stream>>>(edges0, pcnt, E, nps);
        pscan_kernel<<<1, B, 0, stream>>>(pcnt, poffs, sbase, E);
        ppart2_kernel<<<NCHUNK, B, 0, stream>>>(edges0, poffs, pedges, E, nps);
        bcount_kernel<<<8 * BCH, B, 0, stream>>>(pedges, sbase, phist, N, nps);
        merge1_kernel<<<nb, B, 0, stream>>>(phist, cnt, N);
        scan_reduce_kernel<<<nb, 256, 0, stream>>>(cnt, psum, N);
        scan_partials_kernel<<<1, 256, 0, stream>>>(psum, bpre, offsets, N, nb);
        scan_apply_kernel<<<nb, 256, 0, stream>>>(cnt, bpre, offsets, cursor, dinv, N);
        merge2_kernel<<<nb, B, 0, stream>>>(phist, offsets, pbase, N);
        hist_zero_kernel<<<1, NBUCK, 0, stream>>>(hist);
        hist_kernel<<<64, 256, 0, stream>>>(cnt, hist, N);
        hist_scan_kernel<<<1, NBUCK, 0, stream>>>(hist, bcur);
        perm_kernel<<<nb, 256, 0, stream>>>(cnt, bcur, perm, N);
        pscatter_kernel<<<8 * BCH, B, 0, stream>>>(pedges, sbase, pbase, srcs16, N, nps);
    } else {
        const int slice_grid = 8 * 256;
        zero_cnt_kernel<<<(N + B - 1) / B, B, 0, stream>>>(cnt, N);
        count_kernel<<<slice_grid, B, 0, stream>>>(dst, cnt, E, nps);
        scan_reduce_kernel<<<nb, 256, 0, stream>>>(cnt, psum, N);
        scan_partials_kernel<<<1, 256, 0, stream>>>(psum, bpre, offsets, N, nb);
        scan_apply_kernel<<<nb, 256, 0, stream>>>(cnt, bpre, offsets, cursor, dinv, N);
        hist_zero_kernel<<<1, NBUCK, 0, stream>>>(hist);
        hist_kernel<<<64, 256, 0, stream>>>(cnt, hist, N);
        hist_scan_kernel<<<1, NBUCK, 0, stream>>>(hist, bcur);
        perm_kernel<<<nb, 256, 0, stream>>>(cnt, bcur, perm, N);
        scatter_kernel<<<slice_grid, B, 0, stream>>>(src, dst, cursor, sorted_src, E, nps);
    }

    float* hidden = (float*)d_out;
    float* hid_for_prop = deferred ? nullptr : hidden;
    init_kernel<<<((size_t)N * 16 + B - 1) / B, B, 0, stream>>>(
        x, coeffs, dinv, hid_for_prop, ybuf(0, 0), ybuf(0, 1), N);

    const int pgrid = (N + 31) / 32;                 // blocks per half
    const int grid2 = 8 * ((pgrid + 3) / 4);         // XCD-partitioned merged grid
    for (int k = 1; k <= K; ++k) {
        int pin  = deferred ? (k - 1) : ((k - 1) & 1);
        int pout = deferred ? k       : (k & 1);
        if (fastpre) {
            prop2_kernel<unsigned short><<<grid2, B, 0, stream>>>(
                ybuf(pin, 0), ybuf(pin, 1), ybuf(pout, 0), ybuf(pout, 1),
                hid_for_prop, coeffs, k, offsets, srcs16, dinv, perm, N);
        } else {
            prop2_kernel<int><<<grid2, B, 0, stream>>>(
                ybuf(pin, 0), ybuf(pin, 1), ybuf(pout, 0), ybuf(pout, 1),
                hid_for_prop, coeffs, k, offsets, sorted_src, dinv, perm, N);
        }
    }

    if (deferred) {
        final_kernel<<<((size_t)N * 16 + B - 1) / B, B, 0, stream>>>(
            x, coeffs, dinv, ybig, hidden, N, K);
    }
}